// Round 1
// baseline (3092.455 us; speedup 1.0000x reference)
//
#include <hip/hip_runtime.h>
#include <hip/hip_bf16.h>
#include <math.h>

constexpr int Bc = 2, Sc = 2048, Dc = 1024, Hc = 16, HDc = 64;
constexpr int D3 = 3 * Dc;

// ---------------- RMSNorm: one block per row of 1024 ----------------
__global__ __launch_bounds__(256) void rmsnorm_kernel(const float* __restrict__ in,
                                                      float* __restrict__ out) {
  int row = blockIdx.x;
  const float4* x4 = (const float4*)(in + (size_t)row * Dc);
  float4 v = x4[threadIdx.x];
  float s = v.x * v.x + v.y * v.y + v.z * v.z + v.w * v.w;
#pragma unroll
  for (int off = 1; off < 64; off <<= 1) s += __shfl_xor(s, off);
  __shared__ float wsum[4];
  if ((threadIdx.x & 63) == 0) wsum[threadIdx.x >> 6] = s;
  __syncthreads();
  float tot = wsum[0] + wsum[1] + wsum[2] + wsum[3];
  float r = rsqrtf(tot * (1.0f / Dc) + 1.1920928955078125e-07f);
  float4 o;
  o.x = v.x * r; o.y = v.y * r; o.z = v.z * r; o.w = v.w * r;
  ((float4*)(out + (size_t)row * Dc))[threadIdx.x] = o;
}

// ---------------- Householder product Q (64x64), 1 block, 64 threads ----------------
__global__ __launch_bounds__(64) void hh_kernel(const float* __restrict__ vs,
                                                float* __restrict__ Qout) {
  __shared__ float Qm[64][65];
  __shared__ float vsh[64];
  int t = threadIdx.x;
  for (int i = 0; i < 64; ++i) Qm[i][t] = (i == t) ? 1.0f : 0.0f;
  for (int it = 0; it < 32; ++it) {
    __syncthreads();
    vsh[t] = vs[it * 64 + t];
    __syncthreads();
    float nv = 0.0f;
    for (int i = 0; i < 64; ++i) nv += vsh[i] * vsh[i];
    float c = 2.0f / (nv + 1e-8f);
    float wj = 0.0f;  // w[j] = sum_i v[i] * Q[i][j], j = t (own column)
    for (int i = 0; i < 64; ++i) wj += vsh[i] * Qm[i][t];
    for (int i = 0; i < 64; ++i) Qm[i][t] -= c * vsh[i] * wj;
  }
  __syncthreads();
  for (int i = 0; i < 64; ++i) Qout[i * 64 + t] = Qm[i][t];
}

// ---------------- q/k transform: rot(u @ Q^T) @ Q, in-place on qkv ----------------
__global__ __launch_bounds__(64) void qk_rope_kernel(float* __restrict__ qkv,
                                                     const float* __restrict__ Qm,
                                                     const float* __restrict__ rope_pos,
                                                     const float* __restrict__ inv_freq) {
  int idx = blockIdx.x;        // (b*S + s)*H + h
  int which = blockIdx.y;      // 0 = q, 1 = k
  int h = idx & 15;
  int bs = idx >> 4;
  int s = bs & (Sc - 1);
  float* vec = qkv + (size_t)bs * D3 + which * Dc + h * HDc;
  int t = threadIdx.x;
  __shared__ float u[64], r[64];
  u[t] = vec[t];
  __syncthreads();
  float a = 0.0f;  // v1[t] = sum_e u[e] * Q[t][e]   (u @ Q^T)
#pragma unroll 8
  for (int e = 0; e < 64; ++e) a += u[e] * Qm[t * 64 + e];
  r[t] = a;
  __syncthreads();
  float pos = rope_pos[s * 2 + ((t & 31) >> 4)];
  float fr = inv_freq[t & 15];
  float emb = pos * fr;
  float cv = cosf(emb), sv = sinf(emb);
  float partner = (t < 32) ? (-r[t + 32]) : r[t - 32];
  float v2 = a * cv + partner * sv;
  u[t] = v2;
  __syncthreads();
  float b2 = 0.0f;  // v3[t] = sum_e v2[e] * Q[e][t]   (rot @ Q)
#pragma unroll 8
  for (int e = 0; e < 64; ++e) b2 += u[e] * Qm[e * 64 + t];
  vec[t] = b2;
}

// ---------------- GEMM: C[m][n] = dot(A[m,:], W[n,:])  (A: MxK, W: NxK row-major)
// MODE 0: plain   MODE 1: silu(acc1)*acc2 with W2   MODE 2: + R epilogue
template <int MODE>
__global__ __launch_bounds__(256) void gemm_kernel(const float* __restrict__ A,
                                                   const float* __restrict__ W,
                                                   const float* __restrict__ W2,
                                                   const float* __restrict__ R,
                                                   float* __restrict__ C,
                                                   int M, int N, int K) {
  constexpr int BM = 64, BN = 64, BK = 16;
  __shared__ float As[BK][BM + 4];
  __shared__ float Ws[BK][BN + 4];
  __shared__ float Ws2[MODE == 1 ? BK : 1][BN + 4];
  int m0 = blockIdx.y * BM, n0 = blockIdx.x * BN;
  int t = threadIdx.x;
  int tx = t & 15, ty = t >> 4;
  int lrow = t >> 2;
  int lk = (t & 3) * 4;
  float acc[4][4] = {};
  float acc2[4][4] = {};
  const float* Arow = A + (size_t)(m0 + lrow) * K + lk;
  const float* Wrow = W + (size_t)(n0 + lrow) * K + lk;
  const float* W2row = (MODE == 1) ? (W2 + (size_t)(n0 + lrow) * K + lk) : nullptr;
  for (int k0 = 0; k0 < K; k0 += BK) {
    __syncthreads();
    float4 av = *(const float4*)(Arow + k0);
    float4 wv = *(const float4*)(Wrow + k0);
    As[lk + 0][lrow] = av.x; As[lk + 1][lrow] = av.y;
    As[lk + 2][lrow] = av.z; As[lk + 3][lrow] = av.w;
    Ws[lk + 0][lrow] = wv.x; Ws[lk + 1][lrow] = wv.y;
    Ws[lk + 2][lrow] = wv.z; Ws[lk + 3][lrow] = wv.w;
    if (MODE == 1) {
      float4 w2 = *(const float4*)(W2row + k0);
      Ws2[lk + 0][lrow] = w2.x; Ws2[lk + 1][lrow] = w2.y;
      Ws2[lk + 2][lrow] = w2.z; Ws2[lk + 3][lrow] = w2.w;
    }
    __syncthreads();
#pragma unroll
    for (int kk = 0; kk < BK; ++kk) {
      float ra[4], rb[4];
#pragma unroll
      for (int i = 0; i < 4; ++i) ra[i] = As[kk][ty * 4 + i];
#pragma unroll
      for (int j = 0; j < 4; ++j) rb[j] = Ws[kk][tx * 4 + j];
#pragma unroll
      for (int i = 0; i < 4; ++i)
#pragma unroll
        for (int j = 0; j < 4; ++j) acc[i][j] += ra[i] * rb[j];
      if (MODE == 1) {
        float rb2[4];
#pragma unroll
        for (int j = 0; j < 4; ++j) rb2[j] = Ws2[kk][tx * 4 + j];
#pragma unroll
        for (int i = 0; i < 4; ++i)
#pragma unroll
          for (int j = 0; j < 4; ++j) acc2[i][j] += ra[i] * rb2[j];
      }
    }
  }
#pragma unroll
  for (int i = 0; i < 4; ++i) {
    int m = m0 + ty * 4 + i;
    float4 ov;
    float tmp[4];
#pragma unroll
    for (int j = 0; j < 4; ++j) {
      int n = n0 + tx * 4 + j;
      float v = acc[i][j];
      if (MODE == 1) v = (v / (1.0f + expf(-v))) * acc2[i][j];
      if (MODE == 2) v += R[(size_t)m * N + n];
      tmp[j] = v;
    }
    ov.x = tmp[0]; ov.y = tmp[1]; ov.z = tmp[2]; ov.w = tmp[3];
    *(float4*)(C + (size_t)m * N + n0 + tx * 4) = ov;
  }
}

// ---------------- Flash attention (fp32): TQ=32 queries/block, TK=64 key tile ----------------
__global__ __launch_bounds__(256) void attn_kernel(const float* __restrict__ qkv,
                                                   float* __restrict__ out) {
  __shared__ float Qs[32][64];   // broadcast reads -> no pad needed
  __shared__ float Ks[64][65];   // row-indexed by lane -> pad
  __shared__ float Vs[64][64];   // broadcast-ish reads
  __shared__ float Ss[32][65];   // row-indexed by lane -> pad
  int qt = blockIdx.x;           // query tile of 32
  int bh = blockIdx.y;
  int b = bh >> 4, h = bh & 15;
  int t = threadIdx.x;
  const float* base = qkv + (size_t)b * Sc * D3 + h * HDc;
  // load Q tile, scaled by 1/sqrt(64)
#pragma unroll
  for (int j = 0; j < 2; ++j) {
    int idx4 = t + j * 256;
    int r = idx4 >> 4, c4 = idx4 & 15;
    float4 qv = *(const float4*)(base + (size_t)(qt * 32 + r) * D3 + c4 * 4);
    Qs[r][c4 * 4 + 0] = qv.x * 0.125f;
    Qs[r][c4 * 4 + 1] = qv.y * 0.125f;
    Qs[r][c4 * 4 + 2] = qv.z * 0.125f;
    Qs[r][c4 * 4 + 3] = qv.w * 0.125f;
  }
  float m = -INFINITY, l = 0.0f;
  float o[8];
#pragma unroll
  for (int j = 0; j < 8; ++j) o[j] = 0.0f;
  int kk = t & 63, qw = t >> 6;  // score mapping: col kk, rows qw+4i
  int q = t >> 3, sub = t & 7;   // softmax/PV mapping: row q, 8 cols/dims each
  int kt_max = qt >> 1;
  for (int kt = 0; kt <= kt_max; ++kt) {
    __syncthreads();
#pragma unroll
    for (int j = 0; j < 4; ++j) {
      int idx4 = t + j * 256;
      int r = idx4 >> 4, c4 = idx4 & 15;
      const float* krow = base + (size_t)(kt * 64 + r) * D3 + Dc + c4 * 4;
      float4 kv = *(const float4*)krow;
      Ks[r][c4 * 4 + 0] = kv.x; Ks[r][c4 * 4 + 1] = kv.y;
      Ks[r][c4 * 4 + 2] = kv.z; Ks[r][c4 * 4 + 3] = kv.w;
      float4 vv = *(const float4*)(krow + Dc);
      Vs[r][c4 * 4 + 0] = vv.x; Vs[r][c4 * 4 + 1] = vv.y;
      Vs[r][c4 * 4 + 2] = vv.z; Vs[r][c4 * 4 + 3] = vv.w;
    }
    __syncthreads();
    // scores
    float sc[8];
#pragma unroll
    for (int i = 0; i < 8; ++i) sc[i] = 0.0f;
    for (int e = 0; e < 64; ++e) {
      float kv = Ks[kk][e];
#pragma unroll
      for (int i = 0; i < 8; ++i) sc[i] += Qs[qw + 4 * i][e] * kv;
    }
    bool last = (kt == kt_max);
#pragma unroll
    for (int i = 0; i < 8; ++i) {
      int qq = qw + 4 * i;
      float v = sc[i];
      if (last && (kt * 64 + kk) > (qt * 32 + qq)) v = -INFINITY;
      Ss[qq][kk] = v;
    }
    __syncthreads();
    // online softmax for row q
    float mt = -INFINITY;
#pragma unroll
    for (int j = 0; j < 8; ++j) mt = fmaxf(mt, Ss[q][sub * 8 + j]);
    mt = fmaxf(mt, __shfl_xor(mt, 1));
    mt = fmaxf(mt, __shfl_xor(mt, 2));
    mt = fmaxf(mt, __shfl_xor(mt, 4));
    float mnew = fmaxf(m, mt);
    float alpha = expf(m - mnew);
    float sum = 0.0f;
#pragma unroll
    for (int j = 0; j < 8; ++j) {
      float p = expf(Ss[q][sub * 8 + j] - mnew);
      Ss[q][sub * 8 + j] = p;
      sum += p;
    }
    sum += __shfl_xor(sum, 1);
    sum += __shfl_xor(sum, 2);
    sum += __shfl_xor(sum, 4);
    l = l * alpha + sum;
    m = mnew;
    __syncthreads();
#pragma unroll
    for (int j = 0; j < 8; ++j) o[j] *= alpha;
    for (int k2 = 0; k2 < 64; ++k2) {
      float p = Ss[q][k2];
#pragma unroll
      for (int j = 0; j < 8; ++j) o[j] += p * Vs[k2][sub * 8 + j];
    }
  }
  float inv_l = 1.0f / l;
  float* orow = out + ((size_t)(b * Sc + qt * 32 + q)) * Dc + h * HDc + sub * 8;
  float4 o0, o1;
  o0.x = o[0] * inv_l; o0.y = o[1] * inv_l; o0.z = o[2] * inv_l; o0.w = o[3] * inv_l;
  o1.x = o[4] * inv_l; o1.y = o[5] * inv_l; o1.z = o[6] * inv_l; o1.w = o[7] * inv_l;
  *(float4*)orow = o0;
  *(float4*)(orow + 4) = o1;
}

// ---------------- gate fuse: x = resid + o * sigmoid(g + b) ----------------
__global__ __launch_bounds__(256) void gate_kernel(const float* __restrict__ resid,
                                                   const float* __restrict__ o,
                                                   const float* __restrict__ g,
                                                   const float* __restrict__ gb,
                                                   float* __restrict__ out) {
  int i = blockIdx.x * 256 + threadIdx.x;
  float gv = g[i] + gb[i & (Dc - 1)];
  float sg = 1.0f / (1.0f + expf(-gv));
  out[i] = resid[i] + o[i] * sg;
}

extern "C" void kernel_launch(void* const* d_in, const int* in_sizes, int n_in,
                              void* d_out, int out_size, void* d_ws, size_t ws_size,
                              hipStream_t stream) {
  const float* x       = (const float*)d_in[0];
  const float* qkv_w   = (const float*)d_in[2];
  const float* out_w   = (const float*)d_in[3];
  const float* gate_w  = (const float*)d_in[4];
  const float* gate_b  = (const float*)d_in[5];
  const float* w12     = (const float*)d_in[6];
  const float* w3      = (const float*)d_in[7];
  const float* hh_vs   = (const float*)d_in[8];
  const float* inv_freq= (const float*)d_in[9];
  const float* rope_pos= (const float*)d_in[10];
  float* ws = (float*)d_ws;
  // layout (floats): qkv 12.58M | xn/attn_out 4.19M | oproj 4.19M | gate/xn2 4.19M | xmid 4.19M | Q 4096
  // hbuf (16.77M) reuses [0, 16.77M) after attention consumers are done.
  float* qkvb  = ws;
  float* xnb   = ws + 12582912;
  float* oproj = ws + 16777216;
  float* gateb = ws + 20971520;
  float* xmid  = ws + 25165824;
  float* Qb    = ws + 29360128;
  float* hbuf  = ws;
  float* outp  = (float*)d_out;

  rmsnorm_kernel<<<4096, 256, 0, stream>>>(x, xnb);
  hh_kernel<<<1, 64, 0, stream>>>(hh_vs, Qb);
  gemm_kernel<0><<<dim3(3072 / 64, 4096 / 64), 256, 0, stream>>>(
      xnb, qkv_w, nullptr, nullptr, qkvb, 4096, 3072, 1024);
  qk_rope_kernel<<<dim3(Bc * Sc * Hc, 2), 64, 0, stream>>>(qkvb, Qb, rope_pos, inv_freq);
  attn_kernel<<<dim3(64, 32), 256, 0, stream>>>(qkvb, xnb);
  gemm_kernel<0><<<dim3(16, 64), 256, 0, stream>>>(
      xnb, out_w, nullptr, nullptr, oproj, 4096, 1024, 1024);
  gemm_kernel<0><<<dim3(16, 64), 256, 0, stream>>>(
      oproj, gate_w, nullptr, nullptr, gateb, 4096, 1024, 1024);
  gate_kernel<<<16384, 256, 0, stream>>>(x, oproj, gateb, gate_b, xmid);
  rmsnorm_kernel<<<4096, 256, 0, stream>>>(xmid, gateb);  // xn2 -> gateb
  gemm_kernel<1><<<dim3(64, 64), 256, 0, stream>>>(
      gateb, w12, w12 + 4194304, nullptr, hbuf, 4096, 4096, 1024);
  gemm_kernel<2><<<dim3(16, 64), 256, 0, stream>>>(
      hbuf, w3, nullptr, xmid, outp, 4096, 1024, 4096);
}

// Round 2
// 1527.520 us; speedup vs baseline: 2.0245x; 2.0245x over previous
//
#include <hip/hip_runtime.h>
#include <hip/hip_bf16.h>
#include <math.h>

constexpr int Bc = 2, Sc = 2048, Dc = 1024, Hc = 16, HDc = 64;
constexpr int D3 = 3 * Dc;

typedef __bf16 bf16x8 __attribute__((ext_vector_type(8)));
typedef float f32x4 __attribute__((ext_vector_type(4)));

__device__ __forceinline__ void gll16(const void* g, void* l) {
  __builtin_amdgcn_global_load_lds((const __attribute__((address_space(1))) unsigned int*)g,
                                   (__attribute__((address_space(3))) unsigned int*)l,
                                   16, 0, 0);
}

__device__ __forceinline__ unsigned short f2bf(float v) {
  __hip_bfloat16 h = __float2bfloat16(v);
  return *(unsigned short*)&h;
}

// ---------------- fp32 -> bf16 elementwise (4 elems/thread) ----------------
__global__ __launch_bounds__(256) void f2b_kernel(const float* __restrict__ in,
                                                  unsigned short* __restrict__ out) {
  int i = blockIdx.x * 256 + threadIdx.x;
  float4 v = ((const float4*)in)[i];
  ushort4 o;
  o.x = f2bf(v.x); o.y = f2bf(v.y); o.z = f2bf(v.z); o.w = f2bf(v.w);
  ((ushort4*)out)[i] = o;
}

// ---------------- RMSNorm: one block per row of 1024, bf16 out ----------------
__global__ __launch_bounds__(256) void rmsnorm_bf16_kernel(const float* __restrict__ in,
                                                           unsigned short* __restrict__ out) {
  int row = blockIdx.x;
  const float4* x4 = (const float4*)(in + (size_t)row * Dc);
  float4 v = x4[threadIdx.x];
  float s = v.x * v.x + v.y * v.y + v.z * v.z + v.w * v.w;
#pragma unroll
  for (int off = 1; off < 64; off <<= 1) s += __shfl_xor(s, off);
  __shared__ float wsum[4];
  if ((threadIdx.x & 63) == 0) wsum[threadIdx.x >> 6] = s;
  __syncthreads();
  float tot = wsum[0] + wsum[1] + wsum[2] + wsum[3];
  float r = rsqrtf(tot * (1.0f / Dc) + 1.1920928955078125e-07f);
  ushort4 o;
  o.x = f2bf(v.x * r); o.y = f2bf(v.y * r); o.z = f2bf(v.z * r); o.w = f2bf(v.w * r);
  ((ushort4*)(out + (size_t)row * Dc))[threadIdx.x] = o;
}

// ---------------- Householder product Q (64x64), 1 block, 64 threads ----------------
__global__ __launch_bounds__(64) void hh_kernel(const float* __restrict__ vs,
                                                float* __restrict__ Qout) {
  __shared__ float Qm[64][65];
  __shared__ float vsh[64];
  int t = threadIdx.x;
  for (int i = 0; i < 64; ++i) Qm[i][t] = (i == t) ? 1.0f : 0.0f;
  for (int it = 0; it < 32; ++it) {
    __syncthreads();
    vsh[t] = vs[it * 64 + t];
    __syncthreads();
    float nv = 0.0f;
    for (int i = 0; i < 64; ++i) nv += vsh[i] * vsh[i];
    float c = 2.0f / (nv + 1e-8f);
    float wj = 0.0f;
    for (int i = 0; i < 64; ++i) wj += vsh[i] * Qm[i][t];
    for (int i = 0; i < 64; ++i) Qm[i][t] -= c * vsh[i] * wj;
  }
  __syncthreads();
  for (int i = 0; i < 64; ++i) Qout[i * 64 + t] = Qm[i][t];
}

// ---------------- q/k transform: rot(u @ Q^T) @ Q, in-place on qkv ----------------
__global__ __launch_bounds__(64) void qk_rope_kernel(float* __restrict__ qkv,
                                                     const float* __restrict__ Qm,
                                                     const float* __restrict__ rope_pos,
                                                     const float* __restrict__ inv_freq) {
  int idx = blockIdx.x;
  int which = blockIdx.y;
  int h = idx & 15;
  int bs = idx >> 4;
  int s = bs & (Sc - 1);
  float* vec = qkv + (size_t)bs * D3 + which * Dc + h * HDc;
  int t = threadIdx.x;
  __shared__ float u[64], r[64];
  u[t] = vec[t];
  __syncthreads();
  float a = 0.0f;
#pragma unroll 8
  for (int e = 0; e < 64; ++e) a += u[e] * Qm[t * 64 + e];
  r[t] = a;
  __syncthreads();
  float pos = rope_pos[s * 2 + ((t & 31) >> 4)];
  float fr = inv_freq[t & 15];
  float emb = pos * fr;
  float cv = cosf(emb), sv = sinf(emb);
  float partner = (t < 32) ? (-r[t + 32]) : r[t - 32];
  float v2 = a * cv + partner * sv;
  u[t] = v2;
  __syncthreads();
  float b2 = 0.0f;
#pragma unroll 8
  for (int e = 0; e < 64; ++e) b2 += u[e] * Qm[e * 64 + t];
  vec[t] = b2;
}

// ---------------- bf16 MFMA GEMM: C[m][n] = dot(A[m,:], W[n,:]) ----------------
// A: MxK bf16 row-major, W: NxK bf16 row-major. 128x128 tile, BK=32, 4 waves.
// MODE 0: C fp32          MODE 1: C bf16 = silu(A.W^T) * (A.W2^T)   MODE 2: C fp32 = A.W^T + R
template <int MODE>
__global__ __launch_bounds__(256) void mgemm(const unsigned short* __restrict__ A,
                                             const unsigned short* __restrict__ W,
                                             const unsigned short* __restrict__ W2,
                                             const float* __restrict__ R,
                                             void* __restrict__ Cout,
                                             int M, int N, int K) {
  __shared__ unsigned short As[4096];
  __shared__ unsigned short Bs[4096];
  __shared__ unsigned short B2s[(MODE == 1) ? 4096 : 8];
  const int t = threadIdx.x;
  const int lane = t & 63;
  const int wave = t >> 6;
  const int wr = wave >> 1, wc = wave & 1;
  const int m0 = blockIdx.y * 128, n0 = blockIdx.x * 128;
  f32x4 acc[4][4] = {};
  f32x4 acc2[4][4] = {};
  // staging: thread t loads 16B = 8 bf16: row t/4 (+64 for issue 1), k-chunk (t%4)*8
  const int srow = t >> 2;
  const int sch = (t & 3) * 8;
  const unsigned short* Ag = A + (size_t)(m0 + srow) * K + sch;
  const unsigned short* Wg = W + (size_t)(n0 + srow) * K + sch;
  const unsigned short* W2g = (MODE == 1) ? (W2 + (size_t)(n0 + srow) * K + sch) : nullptr;
  const size_t rstep = (size_t)64 * K;
  // fragment read: lane holds [idx=lane&15][k=(lane>>4)*8 + 0..7]
  const int frow = lane & 15;
  const int fk = (lane >> 4) * 8;
  unsigned short* Al0 = As + t * 8;
  unsigned short* Al1 = As + 2048 + t * 8;
  unsigned short* Bl0 = Bs + t * 8;
  unsigned short* Bl1 = Bs + 2048 + t * 8;
  for (int k0 = 0; k0 < K; k0 += 32) {
    __syncthreads();
    gll16(Ag + k0, Al0);
    gll16(Ag + k0 + rstep, Al1);
    gll16(Wg + k0, Bl0);
    gll16(Wg + k0 + rstep, Bl1);
    if (MODE == 1) {
      gll16(W2g + k0, B2s + t * 8);
      gll16(W2g + k0 + rstep, B2s + 2048 + t * 8);
    }
    __syncthreads();
    bf16x8 af[4], bfr[4];
#pragma unroll
    for (int i = 0; i < 4; ++i)
      af[i] = *(const bf16x8*)(As + (wr * 64 + i * 16 + frow) * 32 + fk);
#pragma unroll
    for (int j = 0; j < 4; ++j)
      bfr[j] = *(const bf16x8*)(Bs + (wc * 64 + j * 16 + frow) * 32 + fk);
#pragma unroll
    for (int i = 0; i < 4; ++i)
#pragma unroll
      for (int j = 0; j < 4; ++j)
        acc[i][j] = __builtin_amdgcn_mfma_f32_16x16x32_bf16(af[i], bfr[j], acc[i][j], 0, 0, 0);
    if (MODE == 1) {
      bf16x8 b2f[4];
#pragma unroll
      for (int j = 0; j < 4; ++j)
        b2f[j] = *(const bf16x8*)(B2s + (wc * 64 + j * 16 + frow) * 32 + fk);
#pragma unroll
      for (int i = 0; i < 4; ++i)
#pragma unroll
        for (int j = 0; j < 4; ++j)
          acc2[i][j] = __builtin_amdgcn_mfma_f32_16x16x32_bf16(af[i], b2f[j], acc2[i][j], 0, 0, 0);
    }
  }
  // epilogue: C/D layout col=lane&15, row=(lane>>4)*4+reg
  const int crow = wr * 64 + (lane >> 4) * 4;
  const int ccol = wc * 64 + (lane & 15);
#pragma unroll
  for (int i = 0; i < 4; ++i) {
#pragma unroll
    for (int j = 0; j < 4; ++j) {
#pragma unroll
      for (int r = 0; r < 4; ++r) {
        int row = m0 + crow + i * 16 + r;
        int col = n0 + ccol + j * 16;
        float v = acc[i][j][r];
        if (MODE == 0) {
          ((float*)Cout)[(size_t)row * N + col] = v;
        } else if (MODE == 1) {
          float sv = v / (1.0f + expf(-v));
          ((unsigned short*)Cout)[(size_t)row * N + col] = f2bf(sv * acc2[i][j][r]);
        } else {
          ((float*)Cout)[(size_t)row * N + col] = v + R[(size_t)row * N + col];
        }
      }
    }
  }
}

// ---------------- Flash attention (fp32 in, bf16 out) ----------------
__global__ __launch_bounds__(256) void attn_kernel(const float* __restrict__ qkv,
                                                   unsigned short* __restrict__ out) {
  __shared__ float Qs[32][64];
  __shared__ float Ks[64][65];
  __shared__ float Vs[64][64];
  __shared__ float Ss[32][65];
  int qt = blockIdx.x;
  int bh = blockIdx.y;
  int b = bh >> 4, h = bh & 15;
  int t = threadIdx.x;
  const float* base = qkv + (size_t)b * Sc * D3 + h * HDc;
#pragma unroll
  for (int j = 0; j < 2; ++j) {
    int idx4 = t + j * 256;
    int r = idx4 >> 4, c4 = idx4 & 15;
    float4 qv = *(const float4*)(base + (size_t)(qt * 32 + r) * D3 + c4 * 4);
    Qs[r][c4 * 4 + 0] = qv.x * 0.125f;
    Qs[r][c4 * 4 + 1] = qv.y * 0.125f;
    Qs[r][c4 * 4 + 2] = qv.z * 0.125f;
    Qs[r][c4 * 4 + 3] = qv.w * 0.125f;
  }
  float m = -INFINITY, l = 0.0f;
  float o[8];
#pragma unroll
  for (int j = 0; j < 8; ++j) o[j] = 0.0f;
  int kk = t & 63, qw = t >> 6;
  int q = t >> 3, sub = t & 7;
  int kt_max = qt >> 1;
  for (int kt = 0; kt <= kt_max; ++kt) {
    __syncthreads();
#pragma unroll
    for (int j = 0; j < 4; ++j) {
      int idx4 = t + j * 256;
      int r = idx4 >> 4, c4 = idx4 & 15;
      const float* krow = base + (size_t)(kt * 64 + r) * D3 + Dc + c4 * 4;
      float4 kv = *(const float4*)krow;
      Ks[r][c4 * 4 + 0] = kv.x; Ks[r][c4 * 4 + 1] = kv.y;
      Ks[r][c4 * 4 + 2] = kv.z; Ks[r][c4 * 4 + 3] = kv.w;
      float4 vv = *(const float4*)(krow + Dc);
      Vs[r][c4 * 4 + 0] = vv.x; Vs[r][c4 * 4 + 1] = vv.y;
      Vs[r][c4 * 4 + 2] = vv.z; Vs[r][c4 * 4 + 3] = vv.w;
    }
    __syncthreads();
    float sc[8];
#pragma unroll
    for (int i = 0; i < 8; ++i) sc[i] = 0.0f;
    for (int e = 0; e < 64; ++e) {
      float kv = Ks[kk][e];
#pragma unroll
      for (int i = 0; i < 8; ++i) sc[i] += Qs[qw + 4 * i][e] * kv;
    }
    bool last = (kt == kt_max);
#pragma unroll
    for (int i = 0; i < 8; ++i) {
      int qq = qw + 4 * i;
      float v = sc[i];
      if (last && (kt * 64 + kk) > (qt * 32 + qq)) v = -INFINITY;
      Ss[qq][kk] = v;
    }
    __syncthreads();
    float mt = -INFINITY;
#pragma unroll
    for (int j = 0; j < 8; ++j) mt = fmaxf(mt, Ss[q][sub * 8 + j]);
    mt = fmaxf(mt, __shfl_xor(mt, 1));
    mt = fmaxf(mt, __shfl_xor(mt, 2));
    mt = fmaxf(mt, __shfl_xor(mt, 4));
    float mnew = fmaxf(m, mt);
    float alpha = expf(m - mnew);
    float sum = 0.0f;
#pragma unroll
    for (int j = 0; j < 8; ++j) {
      float p = expf(Ss[q][sub * 8 + j] - mnew);
      Ss[q][sub * 8 + j] = p;
      sum += p;
    }
    sum += __shfl_xor(sum, 1);
    sum += __shfl_xor(sum, 2);
    sum += __shfl_xor(sum, 4);
    l = l * alpha + sum;
    m = mnew;
    __syncthreads();
#pragma unroll
    for (int j = 0; j < 8; ++j) o[j] *= alpha;
    for (int k2 = 0; k2 < 64; ++k2) {
      float p = Ss[q][k2];
#pragma unroll
      for (int j = 0; j < 8; ++j) o[j] += p * Vs[k2][sub * 8 + j];
    }
  }
  float inv_l = 1.0f / l;
  unsigned short* orow = out + ((size_t)(b * Sc + qt * 32 + q)) * Dc + h * HDc + sub * 8;
  ushort4 o0, o1;
  o0.x = f2bf(o[0] * inv_l); o0.y = f2bf(o[1] * inv_l);
  o0.z = f2bf(o[2] * inv_l); o0.w = f2bf(o[3] * inv_l);
  o1.x = f2bf(o[4] * inv_l); o1.y = f2bf(o[5] * inv_l);
  o1.z = f2bf(o[6] * inv_l); o1.w = f2bf(o[7] * inv_l);
  ((ushort4*)orow)[0] = o0;
  ((ushort4*)orow)[1] = o1;
}

// ---------------- gate fuse: xmid = x + o * sigmoid(g + b) ----------------
__global__ __launch_bounds__(256) void gate_kernel(const float* __restrict__ resid,
                                                   const float* __restrict__ o,
                                                   const float* __restrict__ g,
                                                   const float* __restrict__ gb,
                                                   float* __restrict__ out) {
  int i = blockIdx.x * 256 + threadIdx.x;
  float gv = g[i] + gb[i & (Dc - 1)];
  float sg = 1.0f / (1.0f + expf(-gv));
  out[i] = resid[i] + o[i] * sg;
}

extern "C" void kernel_launch(void* const* d_in, const int* in_sizes, int n_in,
                              void* d_out, int out_size, void* d_ws, size_t ws_size,
                              hipStream_t stream) {
  const float* x        = (const float*)d_in[0];
  const float* qkv_w    = (const float*)d_in[2];
  const float* out_w    = (const float*)d_in[3];
  const float* gate_w   = (const float*)d_in[4];
  const float* gate_b   = (const float*)d_in[5];
  const float* w12      = (const float*)d_in[6];
  const float* w3       = (const float*)d_in[7];
  const float* hh_vs    = (const float*)d_in[8];
  const float* inv_freq = (const float*)d_in[9];
  const float* rope_pos = (const float*)d_in[10];
  char* ws = (char*)d_ws;
  // lifetime-based slot layout (bytes), peak 109.07 MB:
  unsigned short* wqkvb  = (unsigned short*)(ws + 0);          // 6.29 MB   [start -> qkv GEMM]
  unsigned short* woutb  = (unsigned short*)(ws + 6291456);    // 2.10 MB   [start -> outproj GEMM]
  unsigned short* wgateb = (unsigned short*)(ws + 8388608);    // 2.10 MB   [start -> gate GEMM]
  float*          xmid   = (float*)(ws + 0);                   // 16.78 MB  [gate fuse -> end]
  unsigned short* slotB  = (unsigned short*)(ws + 16777216);   // 8.39 MB   xn_b | attn_out_b | xn2_b
  float*          oproj  = (float*)(ws + 25165824);            // 16.78 MB  [outproj -> gate fuse]
  unsigned short* w12b   = (unsigned short*)(ws + 25165824);   // 16.78 MB  [after fuse -> w12 GEMM]
  float*          gateb  = (float*)(ws + 41943040);            // 16.78 MB  [gate GEMM -> gate fuse]
  unsigned short* w3b    = (unsigned short*)(ws + 41943040);   // 8.39 MB   [after fuse -> w3 GEMM]
  float*          qkvb   = (float*)(ws + 58720256);            // 50.33 MB  [qkv GEMM -> attn]
  unsigned short* hbufb  = (unsigned short*)(ws + 58720256);   // 33.55 MB  [w12 -> w3 GEMM]
  unsigned short* oprojb = (unsigned short*)(ws + 92274688);   // 8.39 MB   [after outproj -> gate GEMM]
  float*          Qb     = (float*)(ws + 109051904);           // 16 KB
  float* outp = (float*)d_out;

  // weight casts (early ones only; w12/w3 slots still occupied)
  f2b_kernel<<<3072, 256, 0, stream>>>(qkv_w, wqkvb);
  f2b_kernel<<<1024, 256, 0, stream>>>(out_w, woutb);
  f2b_kernel<<<1024, 256, 0, stream>>>(gate_w, wgateb);
  hh_kernel<<<1, 64, 0, stream>>>(hh_vs, Qb);
  rmsnorm_bf16_kernel<<<4096, 256, 0, stream>>>(x, slotB);  // xn bf16
  mgemm<0><<<dim3(24, 32), 256, 0, stream>>>(slotB, wqkvb, nullptr, nullptr, qkvb,
                                             4096, 3072, 1024);
  qk_rope_kernel<<<dim3(Bc * Sc * Hc, 2), 64, 0, stream>>>(qkvb, Qb, rope_pos, inv_freq);
  attn_kernel<<<dim3(64, 32), 256, 0, stream>>>(qkvb, slotB);  // attn_out bf16
  mgemm<0><<<dim3(8, 32), 256, 0, stream>>>(slotB, woutb, nullptr, nullptr, oproj,
                                            4096, 1024, 1024);
  f2b_kernel<<<4096, 256, 0, stream>>>(oproj, oprojb);
  mgemm<0><<<dim3(8, 32), 256, 0, stream>>>(oprojb, wgateb, nullptr, nullptr, gateb,
                                            4096, 1024, 1024);
  gate_kernel<<<16384, 256, 0, stream>>>(x, oproj, gateb, gate_b, xmid);
  f2b_kernel<<<8192, 256, 0, stream>>>(w12, w12b);  // oproj slot now dead
  f2b_kernel<<<4096, 256, 0, stream>>>(w3, w3b);    // gateb slot now dead
  rmsnorm_bf16_kernel<<<4096, 256, 0, stream>>>(xmid, slotB);  // xn2 bf16
  mgemm<1><<<dim3(32, 32), 256, 0, stream>>>(slotB, w12b, w12b + 4194304, nullptr, hbufb,
                                             4096, 4096, 1024);
  mgemm<2><<<dim3(8, 32), 256, 0, stream>>>(hbufb, w3b, nullptr, xmid, outp,
                                            4096, 1024, 4096);
}

// Round 3
// 953.072 us; speedup vs baseline: 3.2447x; 1.6027x over previous
//
#include <hip/hip_runtime.h>
#include <hip/hip_bf16.h>
#include <math.h>

constexpr int Bc = 2, Sc = 2048, Dc = 1024, Hc = 16, HDc = 64;
constexpr int D3 = 3 * Dc;

typedef __bf16 bf16x8 __attribute__((ext_vector_type(8)));
typedef float f32x4 __attribute__((ext_vector_type(4)));

__device__ __forceinline__ void gll16(const void* g, void* l) {
  __builtin_amdgcn_global_load_lds((const __attribute__((address_space(1))) unsigned int*)g,
                                   (__attribute__((address_space(3))) unsigned int*)l,
                                   16, 0, 0);
}

__device__ __forceinline__ unsigned short f2bf(float v) {
  __hip_bfloat16 h = __float2bfloat16(v);
  return *(unsigned short*)&h;
}
__device__ __forceinline__ float b2f(unsigned short u) {
  unsigned v = ((unsigned)u) << 16;
  return __uint_as_float(v);
}

// ---------------- fp32 -> bf16 elementwise (4 elems/thread) ----------------
__global__ __launch_bounds__(256) void f2b_kernel(const float* __restrict__ in,
                                                  unsigned short* __restrict__ out) {
  int i = blockIdx.x * 256 + threadIdx.x;
  float4 v = ((const float4*)in)[i];
  ushort4 o;
  o.x = f2bf(v.x); o.y = f2bf(v.y); o.z = f2bf(v.z); o.w = f2bf(v.w);
  ((ushort4*)out)[i] = o;
}

// ---------------- RMSNorm: one block per row of 1024, bf16 out ----------------
__global__ __launch_bounds__(256) void rmsnorm_bf16_kernel(const float* __restrict__ in,
                                                           unsigned short* __restrict__ out) {
  int row = blockIdx.x;
  const float4* x4 = (const float4*)(in + (size_t)row * Dc);
  float4 v = x4[threadIdx.x];
  float s = v.x * v.x + v.y * v.y + v.z * v.z + v.w * v.w;
#pragma unroll
  for (int off = 1; off < 64; off <<= 1) s += __shfl_xor(s, off);
  __shared__ float wsum[4];
  if ((threadIdx.x & 63) == 0) wsum[threadIdx.x >> 6] = s;
  __syncthreads();
  float tot = wsum[0] + wsum[1] + wsum[2] + wsum[3];
  float r = rsqrtf(tot * (1.0f / Dc) + 1.1920928955078125e-07f);
  ushort4 o;
  o.x = f2bf(v.x * r); o.y = f2bf(v.y * r); o.z = f2bf(v.z * r); o.w = f2bf(v.w * r);
  ((ushort4*)(out + (size_t)row * Dc))[threadIdx.x] = o;
}

// ---------------- Householder product Q (64x64), 1 block, 64 threads ----------------
__global__ __launch_bounds__(64) void hh_kernel(const float* __restrict__ vs,
                                                float* __restrict__ Qout) {
  __shared__ float Qm[64][65];
  __shared__ float vsh[64];
  int t = threadIdx.x;
  for (int i = 0; i < 64; ++i) Qm[i][t] = (i == t) ? 1.0f : 0.0f;
  for (int it = 0; it < 32; ++it) {
    __syncthreads();
    vsh[t] = vs[it * 64 + t];
    __syncthreads();
    float nv = 0.0f;
    for (int i = 0; i < 64; ++i) nv += vsh[i] * vsh[i];
    float c = 2.0f / (nv + 1e-8f);
    float wj = 0.0f;
    for (int i = 0; i < 64; ++i) wj += vsh[i] * Qm[i][t];
    for (int i = 0; i < 64; ++i) Qm[i][t] -= c * vsh[i] * wj;
  }
  __syncthreads();
  for (int i = 0; i < 64; ++i) Qout[i * 64 + t] = Qm[i][t];
}

// ---------------- q/k transform: rot(u @ Q^T) @ Q, bf16 qkv -> head-major bf16 q/k ----------
// q additionally scaled by 1/sqrt(HD)=0.125 (folded attention scale).
__global__ __launch_bounds__(256) void qk_rope_kernel(const unsigned short* __restrict__ qkv,
                                                      const float* __restrict__ Qm,
                                                      const float* __restrict__ rope_pos,
                                                      const float* __restrict__ inv_freq,
                                                      unsigned short* __restrict__ qb,
                                                      unsigned short* __restrict__ kb) {
  __shared__ float u[4][64];
  __shared__ float rv[4][64];
  int which = blockIdx.y;
  int idx = blockIdx.x;  // bs*4 + hgrp
  int hg = idx & 3, bs = idx >> 2;
  int s = bs & (Sc - 1), b = bs >> 11;
  int t = threadIdx.x, lane = t & 63, w = t >> 6;
  int h = hg * 4 + w;
  const unsigned short* vec = qkv + (size_t)bs * D3 + which * Dc + h * 64;
  u[w][lane] = b2f(vec[lane]);
  __syncthreads();
  float a = 0.0f;
#pragma unroll 8
  for (int e = 0; e < 64; ++e) a += u[w][e] * Qm[lane * 64 + e];
  rv[w][lane] = a;
  __syncthreads();
  float pos = rope_pos[s * 2 + ((lane & 31) >> 4)];
  float fr = inv_freq[lane & 15];
  float emb = pos * fr;
  float cv = cosf(emb), sv = sinf(emb);
  float partner = (lane < 32) ? (-rv[w][lane + 32]) : rv[w][lane - 32];
  float v2 = a * cv + partner * sv;
  __syncthreads();
  u[w][lane] = v2;
  __syncthreads();
  float b2 = 0.0f;
#pragma unroll 8
  for (int e = 0; e < 64; ++e) b2 += u[w][e] * Qm[e * 64 + lane];
  if (which == 0) b2 *= 0.125f;
  unsigned short* dst = which ? kb : qb;
  dst[((size_t)(b * Hc + h) * Sc + s) * 64 + lane] = f2bf(b2);
}

// ---------------- V transpose-cast: qkv bf16 [tok][3072] -> vtb [b][h][d][s] bf16 -------
__global__ __launch_bounds__(256) void vt_kernel(const unsigned short* __restrict__ qkv,
                                                 unsigned short* __restrict__ vtb) {
  __shared__ unsigned short tile[64 * 72];
  int st = blockIdx.x;  // s-tile of 64
  int bh = blockIdx.y;
  int b = bh >> 4, h = bh & 15;
  int t = threadIdx.x;
  int srow = t >> 2, c16 = (t & 3) * 16;
  const unsigned short* src =
      qkv + (size_t)(b * Sc + st * 64 + srow) * D3 + 2 * Dc + h * 64 + c16;
  uint4 a0 = *(const uint4*)src;
  uint4 a1 = *(const uint4*)(src + 8);
  *(uint4*)(tile + srow * 72 + c16) = a0;
  *(uint4*)(tile + srow * 72 + c16 + 8) = a1;
  __syncthreads();
  int d = t >> 2, sch = (t & 3) * 16;
  unsigned short tmp[16];
#pragma unroll
  for (int i = 0; i < 16; ++i) tmp[i] = tile[(sch + i) * 72 + d];
  unsigned short* dst = vtb + ((size_t)(bh * 64 + d)) * Sc + st * 64 + sch;
  *(uint4*)dst = *(uint4*)tmp;
  *(uint4*)(dst + 8) = *(uint4*)(tmp + 8);
}

// ---------------- bf16 MFMA GEMM: C[m][n] = dot(A[m,:], W[n,:]) ----------------
// MODE 0: C fp32
// MODE 1: C bf16 = silu(A.W^T) * (A.W2^T)
// MODE 2: C fp32 = A.W^T + R
// MODE 3: C bf16
// MODE 4: Cout fp32 and Cout2 bf16
// MODE 5: Cout fp32 = R + R2 * sigmoid(A.W^T + bias[col])
template <int MODE>
__global__ __launch_bounds__(256) void mgemm(const unsigned short* __restrict__ A,
                                             const unsigned short* __restrict__ W,
                                             const unsigned short* __restrict__ W2,
                                             const float* __restrict__ R,
                                             const float* __restrict__ R2,
                                             const float* __restrict__ bias,
                                             void* __restrict__ Cout,
                                             void* __restrict__ Cout2,
                                             int M, int N, int K) {
  __shared__ unsigned short As[4096];
  __shared__ unsigned short Bs[4096];
  __shared__ unsigned short B2s[(MODE == 1) ? 4096 : 8];
  const int t = threadIdx.x;
  const int lane = t & 63;
  const int wave = t >> 6;
  const int wr = wave >> 1, wc = wave & 1;
  const int m0 = blockIdx.y * 128, n0 = blockIdx.x * 128;
  f32x4 acc[4][4] = {};
  f32x4 acc2[4][4] = {};
  const int srow = t >> 2;
  const int sch = (t & 3) * 8;
  const unsigned short* Ag = A + (size_t)(m0 + srow) * K + sch;
  const unsigned short* Wg = W + (size_t)(n0 + srow) * K + sch;
  const unsigned short* W2g = (MODE == 1) ? (W2 + (size_t)(n0 + srow) * K + sch) : nullptr;
  const size_t rstep = (size_t)64 * K;
  const int frow = lane & 15;
  const int fk = (lane >> 4) * 8;
  unsigned short* Al0 = As + t * 8;
  unsigned short* Al1 = As + 2048 + t * 8;
  unsigned short* Bl0 = Bs + t * 8;
  unsigned short* Bl1 = Bs + 2048 + t * 8;
  for (int k0 = 0; k0 < K; k0 += 32) {
    __syncthreads();
    gll16(Ag + k0, Al0);
    gll16(Ag + k0 + rstep, Al1);
    gll16(Wg + k0, Bl0);
    gll16(Wg + k0 + rstep, Bl1);
    if (MODE == 1) {
      gll16(W2g + k0, B2s + t * 8);
      gll16(W2g + k0 + rstep, B2s + 2048 + t * 8);
    }
    __syncthreads();
    bf16x8 af[4], bfr[4];
#pragma unroll
    for (int i = 0; i < 4; ++i)
      af[i] = *(const bf16x8*)(As + (wr * 64 + i * 16 + frow) * 32 + fk);
#pragma unroll
    for (int j = 0; j < 4; ++j)
      bfr[j] = *(const bf16x8*)(Bs + (wc * 64 + j * 16 + frow) * 32 + fk);
#pragma unroll
    for (int i = 0; i < 4; ++i)
#pragma unroll
      for (int j = 0; j < 4; ++j)
        acc[i][j] = __builtin_amdgcn_mfma_f32_16x16x32_bf16(af[i], bfr[j], acc[i][j], 0, 0, 0);
    if (MODE == 1) {
      bf16x8 b2fg[4];
#pragma unroll
      for (int j = 0; j < 4; ++j)
        b2fg[j] = *(const bf16x8*)(B2s + (wc * 64 + j * 16 + frow) * 32 + fk);
#pragma unroll
      for (int i = 0; i < 4; ++i)
#pragma unroll
        for (int j = 0; j < 4; ++j)
          acc2[i][j] = __builtin_amdgcn_mfma_f32_16x16x32_bf16(af[i], b2fg[j], acc2[i][j], 0, 0, 0);
    }
  }
  const int crow = wr * 64 + (lane >> 4) * 4;
  const int ccol = wc * 64 + (lane & 15);
#pragma unroll
  for (int i = 0; i < 4; ++i) {
#pragma unroll
    for (int j = 0; j < 4; ++j) {
#pragma unroll
      for (int r = 0; r < 4; ++r) {
        int row = m0 + crow + i * 16 + r;
        int col = n0 + ccol + j * 16;
        float v = acc[i][j][r];
        size_t off = (size_t)row * N + col;
        if (MODE == 0) {
          ((float*)Cout)[off] = v;
        } else if (MODE == 1) {
          float sv = v / (1.0f + expf(-v));
          ((unsigned short*)Cout)[off] = f2bf(sv * acc2[i][j][r]);
        } else if (MODE == 2) {
          ((float*)Cout)[off] = v + R[off];
        } else if (MODE == 3) {
          ((unsigned short*)Cout)[off] = f2bf(v);
        } else if (MODE == 4) {
          ((float*)Cout)[off] = v;
          ((unsigned short*)Cout2)[off] = f2bf(v);
        } else {  // MODE 5
          float g = v + bias[col];
          float sg = 1.0f / (1.0f + expf(-g));
          ((float*)Cout)[off] = R[off] + R2[off] * sg;
        }
      }
    }
  }
}

// ---------------- MFMA flash attention ----------------
// qb/kb: [b][h][s][64] bf16 (q pre-scaled by 0.125). vtb: [b][h][d][s] bf16.
// out: [b][s][h*64+d] bf16. Block: one (b,h) x 64-query tile; 4 waves x 16 rows.
__global__ __launch_bounds__(256) void mattn(const unsigned short* __restrict__ qb,
                                             const unsigned short* __restrict__ kb,
                                             const unsigned short* __restrict__ vtb,
                                             unsigned short* __restrict__ out) {
  __shared__ unsigned short Qs[4096];
  __shared__ unsigned short Ks[4096];
  __shared__ unsigned short Vts[4096];
  __shared__ unsigned short Ps[4 * 16 * 72];  // per-wave P, row stride 72 elems (144B)
  const int qt = blockIdx.x, bh = blockIdx.y;
  const int b = bh >> 4, h = bh & 15;
  const int t = threadIdx.x, lane = t & 63, w = t >> 6;
  const int l15 = lane & 15, l4 = lane >> 4;
  const unsigned short* qbase = qb + ((size_t)bh * Sc + qt * 64) * 64;
  const unsigned short* kbase = kb + (size_t)bh * Sc * 64;
  const unsigned short* vbase = vtb + (size_t)bh * 64 * Sc;
  // stage Q once (swizzled chunks: LDS slot c holds global chunk c ^ (row&7))
  {
    int r = t >> 3;
    int cg = (t & 7) ^ (r & 7);
    gll16(qbase + (size_t)r * 64 + cg * 8, Qs + t * 8);
    gll16(qbase + (size_t)(r + 32) * 64 + cg * 8, Qs + 2048 + t * 8);
  }
  bf16x8 qf[2];
  f32x4 oacc[4] = {};
  float mrow[4] = {-INFINITY, -INFINITY, -INFINITY, -INFINITY};
  float lrow[4] = {0.0f, 0.0f, 0.0f, 0.0f};
  unsigned short* pw = Ps + w * 16 * 72;
  for (int kt = 0; kt <= qt; ++kt) {
    __syncthreads();
    {
      int r = t >> 3;
      int cg = (t & 7) ^ (r & 7);
      gll16(kbase + (size_t)(kt * 64 + r) * 64 + cg * 8, Ks + t * 8);
      gll16(kbase + (size_t)(kt * 64 + r + 32) * 64 + cg * 8, Ks + 2048 + t * 8);
      gll16(vbase + (size_t)r * Sc + kt * 64 + cg * 8, Vts + t * 8);
      gll16(vbase + (size_t)(r + 32) * Sc + kt * 64 + cg * 8, Vts + 2048 + t * 8);
    }
    __syncthreads();
    if (kt == 0) {
      int qrow = w * 16 + l15;
      qf[0] = *(const bf16x8*)(Qs + qrow * 64 + ((l4 ^ (l15 & 7)) * 8));
      qf[1] = *(const bf16x8*)(Qs + qrow * 64 + (((4 + l4) ^ (l15 & 7)) * 8));
    }
    // QK^T
    f32x4 sc[4] = {};
#pragma unroll
    for (int kc = 0; kc < 2; ++kc) {
      bf16x8 kf[4];
#pragma unroll
      for (int j = 0; j < 4; ++j) {
        int krow = j * 16 + l15;
        kf[j] = *(const bf16x8*)(Ks + krow * 64 + (((kc * 4 + l4) ^ (l15 & 7)) * 8));
      }
#pragma unroll
      for (int j = 0; j < 4; ++j)
        sc[j] = __builtin_amdgcn_mfma_f32_16x16x32_bf16(qf[kc], kf[j], sc[j], 0, 0, 0);
    }
    if (kt == qt) {
#pragma unroll
      for (int j = 0; j < 4; ++j)
#pragma unroll
        for (int r = 0; r < 4; ++r) {
          int col = j * 16 + l15;
          int row = w * 16 + l4 * 4 + r;
          if (col > row) sc[j][r] = -INFINITY;
        }
    }
    // online softmax (rows distributed: row = l4*4+r within wave's 16)
    float mt[4];
#pragma unroll
    for (int r = 0; r < 4; ++r)
      mt[r] = fmaxf(fmaxf(sc[0][r], sc[1][r]), fmaxf(sc[2][r], sc[3][r]));
#pragma unroll
    for (int r = 0; r < 4; ++r) {
      mt[r] = fmaxf(mt[r], __shfl_xor(mt[r], 1));
      mt[r] = fmaxf(mt[r], __shfl_xor(mt[r], 2));
      mt[r] = fmaxf(mt[r], __shfl_xor(mt[r], 4));
      mt[r] = fmaxf(mt[r], __shfl_xor(mt[r], 8));
    }
    float al[4], rs[4];
#pragma unroll
    for (int r = 0; r < 4; ++r) {
      float mn = fmaxf(mrow[r], mt[r]);
      al[r] = __expf(mrow[r] - mn);
      mrow[r] = mn;
      rs[r] = 0.0f;
    }
#pragma unroll
    for (int j = 0; j < 4; ++j)
#pragma unroll
      for (int r = 0; r < 4; ++r) {
        float p = __expf(sc[j][r] - mrow[r]);
        rs[r] += p;
        pw[(l4 * 4 + r) * 72 + j * 16 + l15] = f2bf(p);
      }
#pragma unroll
    for (int r = 0; r < 4; ++r) {
      rs[r] += __shfl_xor(rs[r], 1);
      rs[r] += __shfl_xor(rs[r], 2);
      rs[r] += __shfl_xor(rs[r], 4);
      rs[r] += __shfl_xor(rs[r], 8);
      lrow[r] = lrow[r] * al[r] + rs[r];
    }
    __asm__ __volatile__("s_waitcnt lgkmcnt(0)" ::: "memory");
#pragma unroll
    for (int j = 0; j < 4; ++j)
#pragma unroll
      for (int r = 0; r < 4; ++r) oacc[j][r] *= al[r];
    // PV
#pragma unroll
    for (int kc = 0; kc < 2; ++kc) {
      bf16x8 pf = *(const bf16x8*)(pw + l15 * 72 + kc * 32 + l4 * 8);
      bf16x8 vf[4];
#pragma unroll
      for (int j = 0; j < 4; ++j) {
        int d = j * 16 + l15;
        vf[j] = *(const bf16x8*)(Vts + d * 64 + (((kc * 4 + l4) ^ (l15 & 7)) * 8));
      }
#pragma unroll
      for (int j = 0; j < 4; ++j)
        oacc[j] = __builtin_amdgcn_mfma_f32_16x16x32_bf16(pf, vf[j], oacc[j], 0, 0, 0);
    }
  }
  float inv[4];
#pragma unroll
  for (int r = 0; r < 4; ++r) inv[r] = 1.0f / lrow[r];
#pragma unroll
  for (int j = 0; j < 4; ++j)
#pragma unroll
    for (int r = 0; r < 4; ++r) {
      int srow = qt * 64 + w * 16 + l4 * 4 + r;
      out[((size_t)(b * Sc + srow)) * Dc + h * 64 + j * 16 + l15] = f2bf(oacc[j][r] * inv[r]);
    }
}

extern "C" void kernel_launch(void* const* d_in, const int* in_sizes, int n_in,
                              void* d_out, int out_size, void* d_ws, size_t ws_size,
                              hipStream_t stream) {
  const float* x        = (const float*)d_in[0];
  const float* qkv_w    = (const float*)d_in[2];
  const float* out_w    = (const float*)d_in[3];
  const float* gate_w   = (const float*)d_in[4];
  const float* gate_b   = (const float*)d_in[5];
  const float* w12      = (const float*)d_in[6];
  const float* w3       = (const float*)d_in[7];
  const float* hh_vs    = (const float*)d_in[8];
  const float* inv_freq = (const float*)d_in[9];
  const float* rope_pos = (const float*)d_in[10];
  char* ws = (char*)d_ws;
  // lifetime-based slots (bytes), peak ~109.07 MB:
  unsigned short* woutb  = (unsigned short*)(ws + 0);          // 2 MiB  [-> outproj]
  unsigned short* wqkvb  = (unsigned short*)(ws + 4194304);    // 6 MiB  [-> qkv GEMM]
  unsigned short* attnb  = (unsigned short*)(ws + 4194304);    // 8 MiB  [mattn -> outproj]
  float*          xmid   = (float*)(ws + 0);                   // 16 MiB [gate GEMM -> end]
  unsigned short* slotB  = (unsigned short*)(ws + 16777216);   // 8 MiB  xn | xn2
  float*          oproj  = (float*)(ws + 25165824);            // 16 MiB [outproj -> gate GEMM]
  unsigned short* w12b   = (unsigned short*)(ws + 25165824);   // 16 MiB [-> w12 GEMM]
  unsigned short* wgateb = (unsigned short*)(ws + 41943040);   // 2 MiB  [-> gate GEMM]
  unsigned short* w3b    = (unsigned short*)(ws + 41943040);   // 8 MiB  [-> w3 GEMM]
  unsigned short* qkvb   = (unsigned short*)(ws + 58720256);   // 24 MiB [qkv GEMM -> rope/vt]
  unsigned short* hbufb  = (unsigned short*)(ws + 58720256);   // 32 MiB [w12 -> w3 GEMM]
  unsigned short* qb     = (unsigned short*)(ws + 83886080);   // 8 MiB  [rope -> mattn]
  unsigned short* oprojb = (unsigned short*)(ws + 83886080);   // 8 MiB  [outproj -> gate GEMM]
  unsigned short* kb     = (unsigned short*)(ws + 92274688);   // 8 MiB
  unsigned short* vtb    = (unsigned short*)(ws + 100663296);  // 8 MiB
  float*          Qb     = (float*)(ws + 109051904);           // 16 KB
  float* outp = (float*)d_out;

  f2b_kernel<<<3072, 256, 0, stream>>>(qkv_w, wqkvb);
  f2b_kernel<<<1024, 256, 0, stream>>>(out_w, woutb);
  f2b_kernel<<<1024, 256, 0, stream>>>(gate_w, wgateb);
  hh_kernel<<<1, 64, 0, stream>>>(hh_vs, Qb);
  rmsnorm_bf16_kernel<<<4096, 256, 0, stream>>>(x, slotB);
  mgemm<3><<<dim3(24, 32), 256, 0, stream>>>(slotB, wqkvb, nullptr, nullptr, nullptr,
                                             nullptr, qkvb, nullptr, 4096, 3072, 1024);
  qk_rope_kernel<<<dim3(16384, 2), 256, 0, stream>>>(qkvb, Qb, rope_pos, inv_freq, qb, kb);
  vt_kernel<<<dim3(32, 32), 256, 0, stream>>>(qkvb, vtb);
  mattn<<<dim3(32, 32), 256, 0, stream>>>(qb, kb, vtb, attnb);
  mgemm<4><<<dim3(8, 32), 256, 0, stream>>>(attnb, woutb, nullptr, nullptr, nullptr,
                                            nullptr, oproj, oprojb, 4096, 1024, 1024);
  mgemm<5><<<dim3(8, 32), 256, 0, stream>>>(oprojb, wgateb, nullptr, x, oproj,
                                            gate_b, xmid, nullptr, 4096, 1024, 1024);
  f2b_kernel<<<8192, 256, 0, stream>>>(w12, w12b);
  f2b_kernel<<<4096, 256, 0, stream>>>(w3, w3b);
  rmsnorm_bf16_kernel<<<4096, 256, 0, stream>>>(xmid, slotB);
  mgemm<1><<<dim3(32, 32), 256, 0, stream>>>(slotB, w12b, w12b + 4194304, nullptr, nullptr,
                                             nullptr, hbufb, nullptr, 4096, 4096, 1024);
  mgemm<2><<<dim3(8, 32), 256, 0, stream>>>(hbufb, w3b, nullptr, xmid, nullptr,
                                            nullptr, outp, nullptr, 4096, 1024, 4096);
}

// Round 4
// 707.609 us; speedup vs baseline: 4.3703x; 1.3469x over previous
//
#include <hip/hip_runtime.h>
#include <hip/hip_bf16.h>
#include <math.h>

constexpr int Bc = 2, Sc = 2048, Dc = 1024, Hc = 16, HDc = 64;
constexpr int D3 = 3 * Dc;

typedef __bf16 bf16x8 __attribute__((ext_vector_type(8)));
typedef float f32x4 __attribute__((ext_vector_type(4)));

__device__ __forceinline__ void gll16(const void* g, void* l) {
  __builtin_amdgcn_global_load_lds((const __attribute__((address_space(1))) unsigned int*)g,
                                   (__attribute__((address_space(3))) unsigned int*)l,
                                   16, 0, 0);
}

__device__ __forceinline__ unsigned short f2bf(float v) {
  __hip_bfloat16 h = __float2bfloat16(v);
  return *(unsigned short*)&h;
}
__device__ __forceinline__ float b2f(unsigned short u) {
  unsigned v = ((unsigned)u) << 16;
  return __uint_as_float(v);
}

// ---------------- fp32 -> bf16 elementwise (4 elems/thread) ----------------
__global__ __launch_bounds__(256) void f2b_kernel(const float* __restrict__ in,
                                                  unsigned short* __restrict__ out) {
  int i = blockIdx.x * 256 + threadIdx.x;
  float4 v = ((const float4*)in)[i];
  ushort4 o;
  o.x = f2bf(v.x); o.y = f2bf(v.y); o.z = f2bf(v.z); o.w = f2bf(v.w);
  ((ushort4*)out)[i] = o;
}

// ---------------- RMSNorm: one block per row of 1024, bf16 out ----------------
__global__ __launch_bounds__(256) void rmsnorm_bf16_kernel(const float* __restrict__ in,
                                                           unsigned short* __restrict__ out) {
  int row = blockIdx.x;
  const float4* x4 = (const float4*)(in + (size_t)row * Dc);
  float4 v = x4[threadIdx.x];
  float s = v.x * v.x + v.y * v.y + v.z * v.z + v.w * v.w;
#pragma unroll
  for (int off = 1; off < 64; off <<= 1) s += __shfl_xor(s, off);
  __shared__ float wsum[4];
  if ((threadIdx.x & 63) == 0) wsum[threadIdx.x >> 6] = s;
  __syncthreads();
  float tot = wsum[0] + wsum[1] + wsum[2] + wsum[3];
  float r = rsqrtf(tot * (1.0f / Dc) + 1.1920928955078125e-07f);
  ushort4 o;
  o.x = f2bf(v.x * r); o.y = f2bf(v.y * r); o.z = f2bf(v.z * r); o.w = f2bf(v.w * r);
  ((ushort4*)(out + (size_t)row * Dc))[threadIdx.x] = o;
}

// ---------------- Householder product Q (64x64), 1 block, 64 threads ----------------
__global__ __launch_bounds__(64) void hh_kernel(const float* __restrict__ vs,
                                                float* __restrict__ Qout) {
  __shared__ float Qm[64][65];
  __shared__ float vsh[64];
  int t = threadIdx.x;
  for (int i = 0; i < 64; ++i) Qm[i][t] = (i == t) ? 1.0f : 0.0f;
  for (int it = 0; it < 32; ++it) {
    __syncthreads();
    vsh[t] = vs[it * 64 + t];
    __syncthreads();
    float nv = 0.0f;
    for (int i = 0; i < 64; ++i) nv += vsh[i] * vsh[i];
    float c = 2.0f / (nv + 1e-8f);
    float wj = 0.0f;
    for (int i = 0; i < 64; ++i) wj += vsh[i] * Qm[i][t];
    for (int i = 0; i < 64; ++i) Qm[i][t] -= c * vsh[i] * wj;
  }
  __syncthreads();
  for (int i = 0; i < 64; ++i) Qout[i * 64 + t] = Qm[i][t];
}

// ---------------- weight fold: out[n][:] = (Q @ W_head)[r][:], q rows scaled 0.125 ----------
// W: [3072][1024] fp32 (only rows 0..2047 processed). out bf16 [n][1024].
__global__ __launch_bounds__(256) void wqk_kernel(const float* __restrict__ W,
                                                  const float* __restrict__ Qm,
                                                  unsigned short* __restrict__ out) {
  int n = blockIdx.x;  // 0..2047
  int r = n & 63;
  int base = n & ~63;
  int t = threadIdx.x;
  float a0 = 0, a1 = 0, a2 = 0, a3 = 0;
  const float4* Wp = (const float4*)(W + (size_t)base * 1024) + t;
#pragma unroll 8
  for (int e = 0; e < 64; ++e) {
    float q = Qm[r * 64 + e];
    float4 wv = Wp[(size_t)e * 256];
    a0 += q * wv.x; a1 += q * wv.y; a2 += q * wv.z; a3 += q * wv.w;
  }
  float sc = (n < 1024) ? 0.125f : 1.0f;
  ushort4 o;
  o.x = f2bf(a0 * sc); o.y = f2bf(a1 * sc); o.z = f2bf(a2 * sc); o.w = f2bf(a3 * sc);
  ((ushort4*)(out + (size_t)n * 1024))[t] = o;
}

// ---------------- rope cos/sin table: tab[s][d] = (cos,sin)(rope_pos[s,d>>4]*invf[d&15]) ----
__global__ __launch_bounds__(256) void rtab_kernel(const float* __restrict__ rope_pos,
                                                   const float* __restrict__ inv_freq,
                                                   float2* __restrict__ tab) {
  int id = blockIdx.x * 256 + threadIdx.x;  // 65536 = 2048*32
  int s = id >> 5, d = id & 31;
  float pos = rope_pos[s * 2 + (d >> 4)];
  float emb = pos * inv_freq[d & 15];
  tab[id] = make_float2(cosf(emb), sinf(emb));
}

// ---------------- RoPE rotate + head-major relayout: qkv bf16 -> qb/kb [b][h][s][64] --------
__global__ __launch_bounds__(256) void rope_kernel(const unsigned short* __restrict__ qkv,
                                                   const float2* __restrict__ tab,
                                                   unsigned short* __restrict__ qb,
                                                   unsigned short* __restrict__ kb) {
  int t = threadIdx.x;
  int gid = blockIdx.x * 64 + (t >> 2);
  int sub = t & 3;
  int h = gid & 15;
  int which = (gid >> 4) & 1;
  int tok = gid >> 5;
  int s = tok & (Sc - 1), b = tok >> 11;
  const unsigned short* src = qkv + (size_t)tok * D3 + which * Dc + h * 64 + sub * 8;
  uint4 lov = *(const uint4*)src;
  uint4 hiv = *(const uint4*)(src + 32);
  const unsigned short* lp = (const unsigned short*)&lov;
  const unsigned short* hp = (const unsigned short*)&hiv;
  unsigned short olo[8], ohi[8];
  const float2* tp = tab + s * 32 + sub * 8;
#pragma unroll
  for (int i = 0; i < 8; ++i) {
    float2 cs = tp[i];
    float lo = b2f(lp[i]), hi = b2f(hp[i]);
    olo[i] = f2bf(lo * cs.x - hi * cs.y);
    ohi[i] = f2bf(hi * cs.x + lo * cs.y);
  }
  unsigned short* dst = (which ? kb : qb) + ((size_t)((b * Hc + h) * Sc + s)) * 64 + sub * 8;
  *(uint4*)dst = *(uint4*)olo;
  *(uint4*)(dst + 32) = *(uint4*)ohi;
}

// ---------------- V transpose-cast: qkv bf16 [tok][3072] -> vtb [b][h][d][s] bf16 -------
__global__ __launch_bounds__(256) void vt_kernel(const unsigned short* __restrict__ qkv,
                                                 unsigned short* __restrict__ vtb) {
  __shared__ unsigned short tile[64 * 72];
  int st = blockIdx.x;
  int bh = blockIdx.y;
  int b = bh >> 4, h = bh & 15;
  int t = threadIdx.x;
  int srow = t >> 2, c16 = (t & 3) * 16;
  const unsigned short* src =
      qkv + (size_t)(b * Sc + st * 64 + srow) * D3 + 2 * Dc + h * 64 + c16;
  uint4 a0 = *(const uint4*)src;
  uint4 a1 = *(const uint4*)(src + 8);
  *(uint4*)(tile + srow * 72 + c16) = a0;
  *(uint4*)(tile + srow * 72 + c16 + 8) = a1;
  __syncthreads();
  int d = t >> 2, sch = (t & 3) * 16;
  unsigned short tmp[16];
#pragma unroll
  for (int i = 0; i < 16; ++i) tmp[i] = tile[(sch + i) * 72 + d];
  unsigned short* dst = vtb + ((size_t)(bh * 64 + d)) * Sc + st * 64 + sch;
  *(uint4*)dst = *(uint4*)tmp;
  *(uint4*)(dst + 8) = *(uint4*)(tmp + 8);
}

// ---------------- bf16 MFMA GEMM: C[m][n] = dot(A[m,:], W[n,:]) ----------------
// MODE 0: C fp32
// MODE 1: C bf16 = silu(A.W^T) * (A.W2^T)
// MODE 2: C fp32 = A.W^T + R
// MODE 3: C bf16
// MODE 4: Cout fp32 and Cout2 bf16
// MODE 5: Cout fp32 = R + R2 * sigmoid(A.W^T + bias[col])
template <int MODE>
__global__ __launch_bounds__(256) void mgemm(const unsigned short* __restrict__ A,
                                             const unsigned short* __restrict__ W,
                                             const unsigned short* __restrict__ W2,
                                             const float* __restrict__ R,
                                             const float* __restrict__ R2,
                                             const float* __restrict__ bias,
                                             void* __restrict__ Cout,
                                             void* __restrict__ Cout2,
                                             int M, int N, int K) {
  __shared__ unsigned short As[4096];
  __shared__ unsigned short Bs[4096];
  __shared__ unsigned short B2s[(MODE == 1) ? 4096 : 8];
  const int t = threadIdx.x;
  const int lane = t & 63;
  const int wave = t >> 6;
  const int wr = wave >> 1, wc = wave & 1;
  const int m0 = blockIdx.y * 128, n0 = blockIdx.x * 128;
  f32x4 acc[4][4] = {};
  f32x4 acc2[4][4] = {};
  const int srow = t >> 2;
  const int sch = (t & 3) * 8;
  const unsigned short* Ag = A + (size_t)(m0 + srow) * K + sch;
  const unsigned short* Wg = W + (size_t)(n0 + srow) * K + sch;
  const unsigned short* W2g = (MODE == 1) ? (W2 + (size_t)(n0 + srow) * K + sch) : nullptr;
  const size_t rstep = (size_t)64 * K;
  const int frow = lane & 15;
  const int fk = (lane >> 4) * 8;
  unsigned short* Al0 = As + t * 8;
  unsigned short* Al1 = As + 2048 + t * 8;
  unsigned short* Bl0 = Bs + t * 8;
  unsigned short* Bl1 = Bs + 2048 + t * 8;
  for (int k0 = 0; k0 < K; k0 += 32) {
    __syncthreads();
    gll16(Ag + k0, Al0);
    gll16(Ag + k0 + rstep, Al1);
    gll16(Wg + k0, Bl0);
    gll16(Wg + k0 + rstep, Bl1);
    if (MODE == 1) {
      gll16(W2g + k0, B2s + t * 8);
      gll16(W2g + k0 + rstep, B2s + 2048 + t * 8);
    }
    __syncthreads();
    bf16x8 af[4], bfr[4];
#pragma unroll
    for (int i = 0; i < 4; ++i)
      af[i] = *(const bf16x8*)(As + (wr * 64 + i * 16 + frow) * 32 + fk);
#pragma unroll
    for (int j = 0; j < 4; ++j)
      bfr[j] = *(const bf16x8*)(Bs + (wc * 64 + j * 16 + frow) * 32 + fk);
#pragma unroll
    for (int i = 0; i < 4; ++i)
#pragma unroll
      for (int j = 0; j < 4; ++j)
        acc[i][j] = __builtin_amdgcn_mfma_f32_16x16x32_bf16(af[i], bfr[j], acc[i][j], 0, 0, 0);
    if (MODE == 1) {
      bf16x8 b2fg[4];
#pragma unroll
      for (int j = 0; j < 4; ++j)
        b2fg[j] = *(const bf16x8*)(B2s + (wc * 64 + j * 16 + frow) * 32 + fk);
#pragma unroll
      for (int i = 0; i < 4; ++i)
#pragma unroll
        for (int j = 0; j < 4; ++j)
          acc2[i][j] = __builtin_amdgcn_mfma_f32_16x16x32_bf16(af[i], b2fg[j], acc2[i][j], 0, 0, 0);
    }
  }
  const int crow = wr * 64 + (lane >> 4) * 4;
  const int ccol = wc * 64 + (lane & 15);
#pragma unroll
  for (int i = 0; i < 4; ++i) {
#pragma unroll
    for (int j = 0; j < 4; ++j) {
#pragma unroll
      for (int r = 0; r < 4; ++r) {
        int row = m0 + crow + i * 16 + r;
        int col = n0 + ccol + j * 16;
        float v = acc[i][j][r];
        size_t off = (size_t)row * N + col;
        if (MODE == 0) {
          ((float*)Cout)[off] = v;
        } else if (MODE == 1) {
          float sv = v / (1.0f + expf(-v));
          ((unsigned short*)Cout)[off] = f2bf(sv * acc2[i][j][r]);
        } else if (MODE == 2) {
          ((float*)Cout)[off] = v + R[off];
        } else if (MODE == 3) {
          ((unsigned short*)Cout)[off] = f2bf(v);
        } else if (MODE == 4) {
          ((float*)Cout)[off] = v;
          ((unsigned short*)Cout2)[off] = f2bf(v);
        } else {  // MODE 5
          float g = v + bias[col];
          float sg = 1.0f / (1.0f + expf(-g));
          ((float*)Cout)[off] = R[off] + R2[off] * sg;
        }
      }
    }
  }
}

// ---------------- MFMA flash attention ----------------
__global__ __launch_bounds__(256) void mattn(const unsigned short* __restrict__ qb,
                                             const unsigned short* __restrict__ kb,
                                             const unsigned short* __restrict__ vtb,
                                             unsigned short* __restrict__ out) {
  __shared__ unsigned short Qs[4096];
  __shared__ unsigned short Ks[4096];
  __shared__ unsigned short Vts[4096];
  __shared__ unsigned short Ps[4 * 16 * 72];
  const int qt = blockIdx.x, bh = blockIdx.y;
  const int b = bh >> 4, h = bh & 15;
  const int t = threadIdx.x, lane = t & 63, w = t >> 6;
  const int l15 = lane & 15, l4 = lane >> 4;
  const unsigned short* qbase = qb + ((size_t)bh * Sc + qt * 64) * 64;
  const unsigned short* kbase = kb + (size_t)bh * Sc * 64;
  const unsigned short* vbase = vtb + (size_t)bh * 64 * Sc;
  {
    int r = t >> 3;
    int cg = (t & 7) ^ (r & 7);
    gll16(qbase + (size_t)r * 64 + cg * 8, Qs + t * 8);
    gll16(qbase + (size_t)(r + 32) * 64 + cg * 8, Qs + 2048 + t * 8);
  }
  bf16x8 qf[2];
  f32x4 oacc[4] = {};
  float mrow[4] = {-INFINITY, -INFINITY, -INFINITY, -INFINITY};
  float lrow[4] = {0.0f, 0.0f, 0.0f, 0.0f};
  unsigned short* pw = Ps + w * 16 * 72;
  for (int kt = 0; kt <= qt; ++kt) {
    __syncthreads();
    {
      int r = t >> 3;
      int cg = (t & 7) ^ (r & 7);
      gll16(kbase + (size_t)(kt * 64 + r) * 64 + cg * 8, Ks + t * 8);
      gll16(kbase + (size_t)(kt * 64 + r + 32) * 64 + cg * 8, Ks + 2048 + t * 8);
      gll16(vbase + (size_t)r * Sc + kt * 64 + cg * 8, Vts + t * 8);
      gll16(vbase + (size_t)(r + 32) * Sc + kt * 64 + cg * 8, Vts + 2048 + t * 8);
    }
    __syncthreads();
    if (kt == 0) {
      int qrow = w * 16 + l15;
      qf[0] = *(const bf16x8*)(Qs + qrow * 64 + ((l4 ^ (l15 & 7)) * 8));
      qf[1] = *(const bf16x8*)(Qs + qrow * 64 + (((4 + l4) ^ (l15 & 7)) * 8));
    }
    f32x4 sc[4] = {};
#pragma unroll
    for (int kc = 0; kc < 2; ++kc) {
      bf16x8 kf[4];
#pragma unroll
      for (int j = 0; j < 4; ++j) {
        int krow = j * 16 + l15;
        kf[j] = *(const bf16x8*)(Ks + krow * 64 + (((kc * 4 + l4) ^ (l15 & 7)) * 8));
      }
#pragma unroll
      for (int j = 0; j < 4; ++j)
        sc[j] = __builtin_amdgcn_mfma_f32_16x16x32_bf16(qf[kc], kf[j], sc[j], 0, 0, 0);
    }
    if (kt == qt) {
#pragma unroll
      for (int j = 0; j < 4; ++j)
#pragma unroll
        for (int r = 0; r < 4; ++r) {
          int col = j * 16 + l15;
          int row = w * 16 + l4 * 4 + r;
          if (col > row) sc[j][r] = -INFINITY;
        }
    }
    float mt[4];
#pragma unroll
    for (int r = 0; r < 4; ++r)
      mt[r] = fmaxf(fmaxf(sc[0][r], sc[1][r]), fmaxf(sc[2][r], sc[3][r]));
#pragma unroll
    for (int r = 0; r < 4; ++r) {
      mt[r] = fmaxf(mt[r], __shfl_xor(mt[r], 1));
      mt[r] = fmaxf(mt[r], __shfl_xor(mt[r], 2));
      mt[r] = fmaxf(mt[r], __shfl_xor(mt[r], 4));
      mt[r] = fmaxf(mt[r], __shfl_xor(mt[r], 8));
    }
    float al[4], rs[4];
#pragma unroll
    for (int r = 0; r < 4; ++r) {
      float mn = fmaxf(mrow[r], mt[r]);
      al[r] = __expf(mrow[r] - mn);
      mrow[r] = mn;
      rs[r] = 0.0f;
    }
#pragma unroll
    for (int j = 0; j < 4; ++j)
#pragma unroll
      for (int r = 0; r < 4; ++r) {
        float p = __expf(sc[j][r] - mrow[r]);
        rs[r] += p;
        pw[(l4 * 4 + r) * 72 + j * 16 + l15] = f2bf(p);
      }
#pragma unroll
    for (int r = 0; r < 4; ++r) {
      rs[r] += __shfl_xor(rs[r], 1);
      rs[r] += __shfl_xor(rs[r], 2);
      rs[r] += __shfl_xor(rs[r], 4);
      rs[r] += __shfl_xor(rs[r], 8);
      lrow[r] = lrow[r] * al[r] + rs[r];
    }
    __asm__ __volatile__("s_waitcnt lgkmcnt(0)" ::: "memory");
#pragma unroll
    for (int j = 0; j < 4; ++j)
#pragma unroll
      for (int r = 0; r < 4; ++r) oacc[j][r] *= al[r];
#pragma unroll
    for (int kc = 0; kc < 2; ++kc) {
      bf16x8 pf = *(const bf16x8*)(pw + l15 * 72 + kc * 32 + l4 * 8);
      bf16x8 vf[4];
#pragma unroll
      for (int j = 0; j < 4; ++j) {
        int d = j * 16 + l15;
        vf[j] = *(const bf16x8*)(Vts + d * 64 + (((kc * 4 + l4) ^ (l15 & 7)) * 8));
      }
#pragma unroll
      for (int j = 0; j < 4; ++j)
        oacc[j] = __builtin_amdgcn_mfma_f32_16x16x32_bf16(pf, vf[j], oacc[j], 0, 0, 0);
    }
  }
  float inv[4];
#pragma unroll
  for (int r = 0; r < 4; ++r) inv[r] = 1.0f / lrow[r];
#pragma unroll
  for (int j = 0; j < 4; ++j)
#pragma unroll
    for (int r = 0; r < 4; ++r) {
      int srow = qt * 64 + w * 16 + l4 * 4 + r;
      out[((size_t)(b * Sc + srow)) * Dc + h * 64 + j * 16 + l15] = f2bf(oacc[j][r] * inv[r]);
    }
}

extern "C" void kernel_launch(void* const* d_in, const int* in_sizes, int n_in,
                              void* d_out, int out_size, void* d_ws, size_t ws_size,
                              hipStream_t stream) {
  const float* x        = (const float*)d_in[0];
  const float* qkv_w    = (const float*)d_in[2];
  const float* out_w    = (const float*)d_in[3];
  const float* gate_w   = (const float*)d_in[4];
  const float* gate_b   = (const float*)d_in[5];
  const float* w12      = (const float*)d_in[6];
  const float* w3       = (const float*)d_in[7];
  const float* hh_vs    = (const float*)d_in[8];
  const float* inv_freq = (const float*)d_in[9];
  const float* rope_pos = (const float*)d_in[10];
  char* ws = (char*)d_ws;
  // lifetime-based slots (bytes), peak ~109.07 MB:
  unsigned short* woutb  = (unsigned short*)(ws + 0);          // 2 MiB  [-> outproj]
  float2*         rtab   = (float2*)(ws + 2097152);            // 512 KB [rtab -> rope]
  unsigned short* wqkvb  = (unsigned short*)(ws + 4194304);    // 6 MiB  [-> qkv GEMM]
  unsigned short* attnb  = (unsigned short*)(ws + 4194304);    // 8 MiB  [mattn -> outproj]
  float*          xmid   = (float*)(ws + 0);                   // 16 MiB [gate GEMM -> end]
  unsigned short* slotB  = (unsigned short*)(ws + 16777216);   // 8 MiB  xn | xn2
  float*          oproj  = (float*)(ws + 25165824);            // 16 MiB [outproj -> gate GEMM]
  unsigned short* w12b   = (unsigned short*)(ws + 25165824);   // 16 MiB [-> w12 GEMM]
  unsigned short* wgateb = (unsigned short*)(ws + 41943040);   // 2 MiB  [-> gate GEMM]
  unsigned short* w3b    = (unsigned short*)(ws + 41943040);   // 8 MiB  [-> w3 GEMM]
  unsigned short* qkvb   = (unsigned short*)(ws + 58720256);   // 24 MiB [qkv GEMM -> rope/vt]
  unsigned short* hbufb  = (unsigned short*)(ws + 58720256);   // 32 MiB [w12 -> w3 GEMM]
  unsigned short* qb     = (unsigned short*)(ws + 83886080);   // 8 MiB  [rope -> mattn]
  unsigned short* oprojb = (unsigned short*)(ws + 83886080);   // 8 MiB  [outproj -> gate GEMM]
  unsigned short* kb     = (unsigned short*)(ws + 92274688);   // 8 MiB
  unsigned short* vtb    = (unsigned short*)(ws + 100663296);  // 8 MiB
  float*          Qb     = (float*)(ws + 109051904);           // 16 KB
  float* outp = (float*)d_out;

  hh_kernel<<<1, 64, 0, stream>>>(hh_vs, Qb);
  rtab_kernel<<<256, 256, 0, stream>>>(rope_pos, inv_freq, rtab);
  wqk_kernel<<<2048, 256, 0, stream>>>(qkv_w, Qb, wqkvb);            // folded q,k weights
  f2b_kernel<<<1024, 256, 0, stream>>>(qkv_w + 2048 * 1024,
                                       wqkvb + 2048 * 1024);          // v weights plain cast
  f2b_kernel<<<1024, 256, 0, stream>>>(out_w, woutb);
  f2b_kernel<<<1024, 256, 0, stream>>>(gate_w, wgateb);
  rmsnorm_bf16_kernel<<<4096, 256, 0, stream>>>(x, slotB);
  mgemm<3><<<dim3(24, 32), 256, 0, stream>>>(slotB, wqkvb, nullptr, nullptr, nullptr,
                                             nullptr, qkvb, nullptr, 4096, 3072, 1024);
  rope_kernel<<<2048, 256, 0, stream>>>(qkvb, rtab, qb, kb);
  vt_kernel<<<dim3(32, 32), 256, 0, stream>>>(qkvb, vtb);
  mattn<<<dim3(32, 32), 256, 0, stream>>>(qb, kb, vtb, attnb);
  mgemm<4><<<dim3(8, 32), 256, 0, stream>>>(attnb, woutb, nullptr, nullptr, nullptr,
                                            nullptr, oproj, oprojb, 4096, 1024, 1024);
  mgemm<5><<<dim3(8, 32), 256, 0, stream>>>(oprojb, wgateb, nullptr, x, oproj,
                                            gate_b, xmid, nullptr, 4096, 1024, 1024);
  f2b_kernel<<<8192, 256, 0, stream>>>(w12, w12b);
  f2b_kernel<<<4096, 256, 0, stream>>>(w3, w3b);
  rmsnorm_bf16_kernel<<<4096, 256, 0, stream>>>(xmid, slotB);
  mgemm<1><<<dim3(32, 32), 256, 0, stream>>>(slotB, w12b, w12b + 4194304, nullptr, nullptr,
                                             nullptr, hbufb, nullptr, 4096, 4096, 1024);
  mgemm<2><<<dim3(8, 32), 256, 0, stream>>>(hbufb, w3b, nullptr, xmid, nullptr,
                                            nullptr, outp, nullptr, 4096, 1024, 4096);
}

// Round 5
// 595.540 us; speedup vs baseline: 5.1927x; 1.1882x over previous
//
#include <hip/hip_runtime.h>
#include <hip/hip_bf16.h>
#include <math.h>

constexpr int Bc = 2, Sc = 2048, Dc = 1024, Hc = 16, HDc = 64;
constexpr int D3 = 3 * Dc;

typedef __bf16 bf16x8 __attribute__((ext_vector_type(8)));
typedef float f32x4 __attribute__((ext_vector_type(4)));

__device__ __forceinline__ void gll16(const void* g, void* l) {
  __builtin_amdgcn_global_load_lds((const __attribute__((address_space(1))) unsigned int*)g,
                                   (__attribute__((address_space(3))) unsigned int*)l,
                                   16, 0, 0);
}

__device__ __forceinline__ unsigned short f2bf(float v) {
  __hip_bfloat16 h = __float2bfloat16(v);
  return *(unsigned short*)&h;
}
__device__ __forceinline__ float b2f(unsigned short u) {
  unsigned v = ((unsigned)u) << 16;
  return __uint_as_float(v);
}

// ---------------- fp32 -> bf16 elementwise (4 elems/thread) ----------------
__global__ __launch_bounds__(256) void f2b_kernel(const float* __restrict__ in,
                                                  unsigned short* __restrict__ out) {
  int i = blockIdx.x * 256 + threadIdx.x;
  float4 v = ((const float4*)in)[i];
  ushort4 o;
  o.x = f2bf(v.x); o.y = f2bf(v.y); o.z = f2bf(v.z); o.w = f2bf(v.w);
  ((ushort4*)out)[i] = o;
}

// ---------------- RMSNorm: one block per row of 1024, bf16 out ----------------
__global__ __launch_bounds__(256) void rmsnorm_bf16_kernel(const float* __restrict__ in,
                                                           unsigned short* __restrict__ out) {
  int row = blockIdx.x;
  const float4* x4 = (const float4*)(in + (size_t)row * Dc);
  float4 v = x4[threadIdx.x];
  float s = v.x * v.x + v.y * v.y + v.z * v.z + v.w * v.w;
#pragma unroll
  for (int off = 1; off < 64; off <<= 1) s += __shfl_xor(s, off);
  __shared__ float wsum[4];
  if ((threadIdx.x & 63) == 0) wsum[threadIdx.x >> 6] = s;
  __syncthreads();
  float tot = wsum[0] + wsum[1] + wsum[2] + wsum[3];
  float r = rsqrtf(tot * (1.0f / Dc) + 1.1920928955078125e-07f);
  ushort4 o;
  o.x = f2bf(v.x * r); o.y = f2bf(v.y * r); o.z = f2bf(v.z * r); o.w = f2bf(v.w * r);
  ((ushort4*)(out + (size_t)row * Dc))[threadIdx.x] = o;
}

// ---------------- Householder product Q (64x64), 1 block, 64 threads ----------------
__global__ __launch_bounds__(64) void hh_kernel(const float* __restrict__ vs,
                                                float* __restrict__ Qout) {
  __shared__ float Qm[64][65];
  __shared__ float vsh[64];
  int t = threadIdx.x;
  for (int i = 0; i < 64; ++i) Qm[i][t] = (i == t) ? 1.0f : 0.0f;
  for (int it = 0; it < 32; ++it) {
    __syncthreads();
    vsh[t] = vs[it * 64 + t];
    __syncthreads();
    float nv = 0.0f;
    for (int i = 0; i < 64; ++i) nv += vsh[i] * vsh[i];
    float c = 2.0f / (nv + 1e-8f);
    float wj = 0.0f;
    for (int i = 0; i < 64; ++i) wj += vsh[i] * Qm[i][t];
    for (int i = 0; i < 64; ++i) Qm[i][t] -= c * vsh[i] * wj;
  }
  __syncthreads();
  for (int i = 0; i < 64; ++i) Qout[i * 64 + t] = Qm[i][t];
}

// ---------------- weight fold: out[n][:] = (Q @ W_head)[r][:], q rows scaled 0.125 ----------
__global__ __launch_bounds__(256) void wqk_kernel(const float* __restrict__ W,
                                                  const float* __restrict__ Qm,
                                                  unsigned short* __restrict__ out) {
  int n = blockIdx.x;  // 0..2047
  int r = n & 63;
  int base = n & ~63;
  int t = threadIdx.x;
  float a0 = 0, a1 = 0, a2 = 0, a3 = 0;
  const float4* Wp = (const float4*)(W + (size_t)base * 1024) + t;
#pragma unroll 8
  for (int e = 0; e < 64; ++e) {
    float q = Qm[r * 64 + e];
    float4 wv = Wp[(size_t)e * 256];
    a0 += q * wv.x; a1 += q * wv.y; a2 += q * wv.z; a3 += q * wv.w;
  }
  float sc = (n < 1024) ? 0.125f : 1.0f;
  ushort4 o;
  o.x = f2bf(a0 * sc); o.y = f2bf(a1 * sc); o.z = f2bf(a2 * sc); o.w = f2bf(a3 * sc);
  ((ushort4*)(out + (size_t)n * 1024))[t] = o;
}

// ---------------- rope cos/sin table ----------------
__global__ __launch_bounds__(256) void rtab_kernel(const float* __restrict__ rope_pos,
                                                   const float* __restrict__ inv_freq,
                                                   float2* __restrict__ tab) {
  int id = blockIdx.x * 256 + threadIdx.x;  // 65536 = 2048*32
  int s = id >> 5, d = id & 31;
  float pos = rope_pos[s * 2 + (d >> 4)];
  float emb = pos * inv_freq[d & 15];
  tab[id] = make_float2(cosf(emb), sinf(emb));
}

// ---------------- RoPE rotate + head-major relayout ----------------
__global__ __launch_bounds__(256) void rope_kernel(const unsigned short* __restrict__ qkv,
                                                   const float2* __restrict__ tab,
                                                   unsigned short* __restrict__ qb,
                                                   unsigned short* __restrict__ kb) {
  int t = threadIdx.x;
  int gid = blockIdx.x * 64 + (t >> 2);
  int sub = t & 3;
  int h = gid & 15;
  int which = (gid >> 4) & 1;
  int tok = gid >> 5;
  int s = tok & (Sc - 1), b = tok >> 11;
  const unsigned short* src = qkv + (size_t)tok * D3 + which * Dc + h * 64 + sub * 8;
  uint4 lov = *(const uint4*)src;
  uint4 hiv = *(const uint4*)(src + 32);
  const unsigned short* lp = (const unsigned short*)&lov;
  const unsigned short* hp = (const unsigned short*)&hiv;
  unsigned short olo[8], ohi[8];
  const float2* tp = tab + s * 32 + sub * 8;
#pragma unroll
  for (int i = 0; i < 8; ++i) {
    float2 cs = tp[i];
    float lo = b2f(lp[i]), hi = b2f(hp[i]);
    olo[i] = f2bf(lo * cs.x - hi * cs.y);
    ohi[i] = f2bf(hi * cs.x + lo * cs.y);
  }
  unsigned short* dst = (which ? kb : qb) + ((size_t)((b * Hc + h) * Sc + s)) * 64 + sub * 8;
  *(uint4*)dst = *(uint4*)olo;
  *(uint4*)(dst + 32) = *(uint4*)ohi;
}

// ---------------- V transpose-cast ----------------
__global__ __launch_bounds__(256) void vt_kernel(const unsigned short* __restrict__ qkv,
                                                 unsigned short* __restrict__ vtb) {
  __shared__ unsigned short tile[64 * 72];
  int st = blockIdx.x;
  int bh = blockIdx.y;
  int b = bh >> 4, h = bh & 15;
  int t = threadIdx.x;
  int srow = t >> 2, c16 = (t & 3) * 16;
  const unsigned short* src =
      qkv + (size_t)(b * Sc + st * 64 + srow) * D3 + 2 * Dc + h * 64 + c16;
  uint4 a0 = *(const uint4*)src;
  uint4 a1 = *(const uint4*)(src + 8);
  *(uint4*)(tile + srow * 72 + c16) = a0;
  *(uint4*)(tile + srow * 72 + c16 + 8) = a1;
  __syncthreads();
  int d = t >> 2, sch = (t & 3) * 16;
  unsigned short tmp[16];
#pragma unroll
  for (int i = 0; i < 16; ++i) tmp[i] = tile[(sch + i) * 72 + d];
  unsigned short* dst = vtb + ((size_t)(bh * 64 + d)) * Sc + st * 64 + sch;
  *(uint4*)dst = *(uint4*)tmp;
  *(uint4*)(dst + 8) = *(uint4*)(tmp + 8);
}

// ---------------- bf16 MFMA GEMM, 128x128 tile ----------------
// MODE 1: C bf16 = silu(A.W^T) * (A.W2^T)   MODE 3: C bf16
template <int MODE>
__global__ __launch_bounds__(256, 2) void mgemm(const unsigned short* __restrict__ A,
                                                const unsigned short* __restrict__ W,
                                                const unsigned short* __restrict__ W2,
                                                void* __restrict__ Cout,
                                                int M, int N, int K) {
  __shared__ unsigned short As[4096];
  __shared__ unsigned short Bs[4096];
  __shared__ unsigned short B2s[(MODE == 1) ? 4096 : 8];
  const int t = threadIdx.x;
  const int lane = t & 63;
  const int wave = t >> 6;
  const int wr = wave >> 1, wc = wave & 1;
  const int m0 = blockIdx.y * 128, n0 = blockIdx.x * 128;
  f32x4 acc[4][4] = {};
  f32x4 acc2[4][4] = {};
  const int srow = t >> 2;
  const int sch = (t & 3) * 8;
  const unsigned short* Ag = A + (size_t)(m0 + srow) * K + sch;
  const unsigned short* Wg = W + (size_t)(n0 + srow) * K + sch;
  const unsigned short* W2g = (MODE == 1) ? (W2 + (size_t)(n0 + srow) * K + sch) : nullptr;
  const size_t rstep = (size_t)64 * K;
  const int frow = lane & 15;
  const int fk = (lane >> 4) * 8;
  for (int k0 = 0; k0 < K; k0 += 32) {
    __syncthreads();
    gll16(Ag + k0, As + t * 8);
    gll16(Ag + k0 + rstep, As + 2048 + t * 8);
    gll16(Wg + k0, Bs + t * 8);
    gll16(Wg + k0 + rstep, Bs + 2048 + t * 8);
    if (MODE == 1) {
      gll16(W2g + k0, B2s + t * 8);
      gll16(W2g + k0 + rstep, B2s + 2048 + t * 8);
    }
    __syncthreads();
    bf16x8 af[4], bq[4];
#pragma unroll
    for (int i = 0; i < 4; ++i)
      af[i] = *(const bf16x8*)(As + (wr * 64 + i * 16 + frow) * 32 + fk);
#pragma unroll
    for (int j = 0; j < 4; ++j)
      bq[j] = *(const bf16x8*)(Bs + (wc * 64 + j * 16 + frow) * 32 + fk);
#pragma unroll
    for (int i = 0; i < 4; ++i)
#pragma unroll
      for (int j = 0; j < 4; ++j)
        acc[i][j] = __builtin_amdgcn_mfma_f32_16x16x32_bf16(af[i], bq[j], acc[i][j], 0, 0, 0);
    if (MODE == 1) {
#pragma unroll
      for (int j = 0; j < 4; ++j)
        bq[j] = *(const bf16x8*)(B2s + (wc * 64 + j * 16 + frow) * 32 + fk);
#pragma unroll
      for (int i = 0; i < 4; ++i)
#pragma unroll
        for (int j = 0; j < 4; ++j)
          acc2[i][j] = __builtin_amdgcn_mfma_f32_16x16x32_bf16(af[i], bq[j], acc2[i][j], 0, 0, 0);
    }
  }
  const int crow = wr * 64 + (lane >> 4) * 4;
  const int ccol = wc * 64 + (lane & 15);
#pragma unroll
  for (int i = 0; i < 4; ++i) {
#pragma unroll
    for (int j = 0; j < 4; ++j) {
#pragma unroll
      for (int r = 0; r < 4; ++r) {
        int row = m0 + crow + i * 16 + r;
        int col = n0 + ccol + j * 16;
        float v = acc[i][j][r];
        size_t off = (size_t)row * N + col;
        if (MODE == 1) {
          float sv = v / (1.0f + expf(-v));
          ((unsigned short*)Cout)[off] = f2bf(sv * acc2[i][j][r]);
        } else {
          ((unsigned short*)Cout)[off] = f2bf(v);
        }
      }
    }
  }
}

// ---------------- bf16 MFMA GEMM, 64x128 tile (for N=1024 GEMMs: more blocks) ----------
// waves 2x2, wave tile 32x64, acc[2][4] (32 AGPR)
// MODE 2: C fp32 = A.W^T + R
// MODE 4: Cout fp32 and Cout2 bf16
// MODE 5: Cout fp32 = R + R2 * sigmoid(A.W^T + bias[col])
template <int MODE>
__global__ __launch_bounds__(256, 3) void mgemm64(const unsigned short* __restrict__ A,
                                                  const unsigned short* __restrict__ W,
                                                  const float* __restrict__ R,
                                                  const float* __restrict__ R2,
                                                  const float* __restrict__ bias,
                                                  void* __restrict__ Cout,
                                                  void* __restrict__ Cout2,
                                                  int M, int N, int K) {
  __shared__ unsigned short As[2048];
  __shared__ unsigned short Bs[4096];
  const int t = threadIdx.x;
  const int lane = t & 63;
  const int wave = t >> 6;
  const int wr = wave >> 1, wc = wave & 1;
  const int m0 = blockIdx.y * 64, n0 = blockIdx.x * 128;
  f32x4 acc[2][4] = {};
  const int srow = t >> 2;
  const int sch = (t & 3) * 8;
  const unsigned short* Ag = A + (size_t)(m0 + srow) * K + sch;
  const unsigned short* Wg = W + (size_t)(n0 + srow) * K + sch;
  const size_t rstep = (size_t)64 * K;
  const int frow = lane & 15;
  const int fk = (lane >> 4) * 8;
  for (int k0 = 0; k0 < K; k0 += 32) {
    __syncthreads();
    gll16(Ag + k0, As + t * 8);
    gll16(Wg + k0, Bs + t * 8);
    gll16(Wg + k0 + rstep, Bs + 2048 + t * 8);
    __syncthreads();
    bf16x8 af[2], bq[4];
#pragma unroll
    for (int i = 0; i < 2; ++i)
      af[i] = *(const bf16x8*)(As + (wr * 32 + i * 16 + frow) * 32 + fk);
#pragma unroll
    for (int j = 0; j < 4; ++j)
      bq[j] = *(const bf16x8*)(Bs + (wc * 64 + j * 16 + frow) * 32 + fk);
#pragma unroll
    for (int i = 0; i < 2; ++i)
#pragma unroll
      for (int j = 0; j < 4; ++j)
        acc[i][j] = __builtin_amdgcn_mfma_f32_16x16x32_bf16(af[i], bq[j], acc[i][j], 0, 0, 0);
  }
  const int crow = wr * 32 + (lane >> 4) * 4;
  const int ccol = wc * 64 + (lane & 15);
#pragma unroll
  for (int i = 0; i < 2; ++i) {
#pragma unroll
    for (int j = 0; j < 4; ++j) {
#pragma unroll
      for (int r = 0; r < 4; ++r) {
        int row = m0 + crow + i * 16 + r;
        int col = n0 + ccol + j * 16;
        float v = acc[i][j][r];
        size_t off = (size_t)row * N + col;
        if (MODE == 2) {
          ((float*)Cout)[off] = v + R[off];
        } else if (MODE == 4) {
          ((float*)Cout)[off] = v;
          ((unsigned short*)Cout2)[off] = f2bf(v);
        } else {  // MODE 5
          float g = v + bias[col];
          float sg = 1.0f / (1.0f + expf(-g));
          ((float*)Cout)[off] = R[off] + R2[off] * sg;
        }
      }
    }
  }
}

// ---------------- MFMA flash attention ----------------
__global__ __launch_bounds__(256) void mattn(const unsigned short* __restrict__ qb,
                                             const unsigned short* __restrict__ kb,
                                             const unsigned short* __restrict__ vtb,
                                             unsigned short* __restrict__ out) {
  __shared__ unsigned short Qs[4096];
  __shared__ unsigned short Ks[4096];
  __shared__ unsigned short Vts[4096];
  __shared__ unsigned short Ps[4 * 16 * 72];
  const int qt = blockIdx.x, bh = blockIdx.y;
  const int b = bh >> 4, h = bh & 15;
  const int t = threadIdx.x, lane = t & 63, w = t >> 6;
  const int l15 = lane & 15, l4 = lane >> 4;
  const unsigned short* qbase = qb + ((size_t)bh * Sc + qt * 64) * 64;
  const unsigned short* kbase = kb + (size_t)bh * Sc * 64;
  const unsigned short* vbase = vtb + (size_t)bh * 64 * Sc;
  {
    int r = t >> 3;
    int cg = (t & 7) ^ (r & 7);
    gll16(qbase + (size_t)r * 64 + cg * 8, Qs + t * 8);
    gll16(qbase + (size_t)(r + 32) * 64 + cg * 8, Qs + 2048 + t * 8);
  }
  bf16x8 qf[2];
  f32x4 oacc[4] = {};
  float mrow[4] = {-INFINITY, -INFINITY, -INFINITY, -INFINITY};
  float lrow[4] = {0.0f, 0.0f, 0.0f, 0.0f};
  unsigned short* pw = Ps + w * 16 * 72;
  for (int kt = 0; kt <= qt; ++kt) {
    __syncthreads();
    {
      int r = t >> 3;
      int cg = (t & 7) ^ (r & 7);
      gll16(kbase + (size_t)(kt * 64 + r) * 64 + cg * 8, Ks + t * 8);
      gll16(kbase + (size_t)(kt * 64 + r + 32) * 64 + cg * 8, Ks + 2048 + t * 8);
      gll16(vbase + (size_t)r * Sc + kt * 64 + cg * 8, Vts + t * 8);
      gll16(vbase + (size_t)(r + 32) * Sc + kt * 64 + cg * 8, Vts + 2048 + t * 8);
    }
    __syncthreads();
    if (kt == 0) {
      int qrow = w * 16 + l15;
      qf[0] = *(const bf16x8*)(Qs + qrow * 64 + ((l4 ^ (l15 & 7)) * 8));
      qf[1] = *(const bf16x8*)(Qs + qrow * 64 + (((4 + l4) ^ (l15 & 7)) * 8));
    }
    f32x4 sc[4] = {};
#pragma unroll
    for (int kc = 0; kc < 2; ++kc) {
      bf16x8 kf[4];
#pragma unroll
      for (int j = 0; j < 4; ++j) {
        int krow = j * 16 + l15;
        kf[j] = *(const bf16x8*)(Ks + krow * 64 + (((kc * 4 + l4) ^ (l15 & 7)) * 8));
      }
#pragma unroll
      for (int j = 0; j < 4; ++j)
        sc[j] = __builtin_amdgcn_mfma_f32_16x16x32_bf16(qf[kc], kf[j], sc[j], 0, 0, 0);
    }
    if (kt == qt) {
#pragma unroll
      for (int j = 0; j < 4; ++j)
#pragma unroll
        for (int r = 0; r < 4; ++r) {
          int col = j * 16 + l15;
          int row = w * 16 + l4 * 4 + r;
          if (col > row) sc[j][r] = -INFINITY;
        }
    }
    float mt[4];
#pragma unroll
    for (int r = 0; r < 4; ++r)
      mt[r] = fmaxf(fmaxf(sc[0][r], sc[1][r]), fmaxf(sc[2][r], sc[3][r]));
#pragma unroll
    for (int r = 0; r < 4; ++r) {
      mt[r] = fmaxf(mt[r], __shfl_xor(mt[r], 1));
      mt[r] = fmaxf(mt[r], __shfl_xor(mt[r], 2));
      mt[r] = fmaxf(mt[r], __shfl_xor(mt[r], 4));
      mt[r] = fmaxf(mt[r], __shfl_xor(mt[r], 8));
    }
    float al[4], rs[4];
#pragma unroll
    for (int r = 0; r < 4; ++r) {
      float mn = fmaxf(mrow[r], mt[r]);
      al[r] = __expf(mrow[r] - mn);
      mrow[r] = mn;
      rs[r] = 0.0f;
    }
#pragma unroll
    for (int j = 0; j < 4; ++j)
#pragma unroll
      for (int r = 0; r < 4; ++r) {
        float p = __expf(sc[j][r] - mrow[r]);
        rs[r] += p;
        pw[(l4 * 4 + r) * 72 + j * 16 + l15] = f2bf(p);
      }
#pragma unroll
    for (int r = 0; r < 4; ++r) {
      rs[r] += __shfl_xor(rs[r], 1);
      rs[r] += __shfl_xor(rs[r], 2);
      rs[r] += __shfl_xor(rs[r], 4);
      rs[r] += __shfl_xor(rs[r], 8);
      lrow[r] = lrow[r] * al[r] + rs[r];
    }
    __asm__ __volatile__("s_waitcnt lgkmcnt(0)" ::: "memory");
#pragma unroll
    for (int j = 0; j < 4; ++j)
#pragma unroll
      for (int r = 0; r < 4; ++r) oacc[j][r] *= al[r];
#pragma unroll
    for (int kc = 0; kc < 2; ++kc) {
      bf16x8 pf = *(const bf16x8*)(pw + l15 * 72 + kc * 32 + l4 * 8);
      bf16x8 vf[4];
#pragma unroll
      for (int j = 0; j < 4; ++j) {
        int d = j * 16 + l15;
        vf[j] = *(const bf16x8*)(Vts + d * 64 + (((kc * 4 + l4) ^ (l15 & 7)) * 8));
      }
#pragma unroll
      for (int j = 0; j < 4; ++j)
        oacc[j] = __builtin_amdgcn_mfma_f32_16x16x32_bf16(pf, vf[j], oacc[j], 0, 0, 0);
    }
  }
  float inv[4];
#pragma unroll
  for (int r = 0; r < 4; ++r) inv[r] = 1.0f / lrow[r];
#pragma unroll
  for (int j = 0; j < 4; ++j)
#pragma unroll
    for (int r = 0; r < 4; ++r) {
      int srow = qt * 64 + w * 16 + l4 * 4 + r;
      out[((size_t)(b * Sc + srow)) * Dc + h * 64 + j * 16 + l15] = f2bf(oacc[j][r] * inv[r]);
    }
}

extern "C" void kernel_launch(void* const* d_in, const int* in_sizes, int n_in,
                              void* d_out, int out_size, void* d_ws, size_t ws_size,
                              hipStream_t stream) {
  const float* x        = (const float*)d_in[0];
  const float* qkv_w    = (const float*)d_in[2];
  const float* out_w    = (const float*)d_in[3];
  const float* gate_w   = (const float*)d_in[4];
  const float* gate_b   = (const float*)d_in[5];
  const float* w12      = (const float*)d_in[6];
  const float* w3       = (const float*)d_in[7];
  const float* hh_vs    = (const float*)d_in[8];
  const float* inv_freq = (const float*)d_in[9];
  const float* rope_pos = (const float*)d_in[10];
  char* ws = (char*)d_ws;
  // lifetime-based slots (bytes), peak ~109.07 MB:
  unsigned short* woutb  = (unsigned short*)(ws + 0);          // 2 MiB  [-> outproj]
  float2*         rtab   = (float2*)(ws + 2097152);            // 512 KB [rtab -> rope]
  unsigned short* wqkvb  = (unsigned short*)(ws + 4194304);    // 6 MiB  [-> qkv GEMM]
  unsigned short* attnb  = (unsigned short*)(ws + 4194304);    // 8 MiB  [mattn -> outproj]
  float*          xmid   = (float*)(ws + 0);                   // 16 MiB [gate GEMM -> end]
  unsigned short* slotB  = (unsigned short*)(ws + 16777216);   // 8 MiB  xn | xn2
  float*          oproj  = (float*)(ws + 25165824);            // 16 MiB [outproj -> gate GEMM]
  unsigned short* w12b   = (unsigned short*)(ws + 25165824);   // 16 MiB [-> w12 GEMM]
  unsigned short* wgateb = (unsigned short*)(ws + 41943040);   // 2 MiB  [-> gate GEMM]
  unsigned short* w3b    = (unsigned short*)(ws + 41943040);   // 8 MiB  [-> w3 GEMM]
  unsigned short* qkvb   = (unsigned short*)(ws + 58720256);   // 24 MiB [qkv GEMM -> rope/vt]
  unsigned short* hbufb  = (unsigned short*)(ws + 58720256);   // 32 MiB [w12 -> w3 GEMM]
  unsigned short* qb     = (unsigned short*)(ws + 83886080);   // 8 MiB  [rope -> mattn]
  unsigned short* oprojb = (unsigned short*)(ws + 83886080);   // 8 MiB  [outproj -> gate GEMM]
  unsigned short* kb     = (unsigned short*)(ws + 92274688);   // 8 MiB
  unsigned short* vtb    = (unsigned short*)(ws + 100663296);  // 8 MiB
  float*          Qb     = (float*)(ws + 109051904);           // 16 KB
  float* outp = (float*)d_out;

  hh_kernel<<<1, 64, 0, stream>>>(hh_vs, Qb);
  rtab_kernel<<<256, 256, 0, stream>>>(rope_pos, inv_freq, rtab);
  wqk_kernel<<<2048, 256, 0, stream>>>(qkv_w, Qb, wqkvb);            // folded q,k weights
  f2b_kernel<<<1024, 256, 0, stream>>>(qkv_w + 2048 * 1024,
                                       wqkvb + 2048 * 1024);          // v weights plain cast
  f2b_kernel<<<1024, 256, 0, stream>>>(out_w, woutb);
  f2b_kernel<<<1024, 256, 0, stream>>>(gate_w, wgateb);
  rmsnorm_bf16_kernel<<<4096, 256, 0, stream>>>(x, slotB);
  mgemm<3><<<dim3(24, 32), 256, 0, stream>>>(slotB, wqkvb, nullptr, qkvb, 4096, 3072, 1024);
  rope_kernel<<<2048, 256, 0, stream>>>(qkvb, rtab, qb, kb);
  vt_kernel<<<dim3(32, 32), 256, 0, stream>>>(qkvb, vtb);
  mattn<<<dim3(32, 32), 256, 0, stream>>>(qb, kb, vtb, attnb);
  mgemm64<4><<<dim3(8, 64), 256, 0, stream>>>(attnb, woutb, nullptr, nullptr, nullptr,
                                              oproj, oprojb, 4096, 1024, 1024);
  mgemm64<5><<<dim3(8, 64), 256, 0, stream>>>(oprojb, wgateb, x, oproj, gate_b,
                                              xmid, nullptr, 4096, 1024, 1024);
  f2b_kernel<<<8192, 256, 0, stream>>>(w12, w12b);
  f2b_kernel<<<4096, 256, 0, stream>>>(w3, w3b);
  rmsnorm_bf16_kernel<<<4096, 256, 0, stream>>>(xmid, slotB);
  mgemm<1><<<dim3(32, 32), 256, 0, stream>>>(slotB, w12b, w12b + 4194304, hbufb,
                                             4096, 4096, 1024);
  mgemm64<2><<<dim3(8, 64), 256, 0, stream>>>(hbufb, w3b, xmid, nullptr, nullptr,
                                              outp, nullptr, 4096, 1024, 4096);
}

// Round 6
// 559.786 us; speedup vs baseline: 5.5244x; 1.0639x over previous
//
#include <hip/hip_runtime.h>
#include <hip/hip_bf16.h>
#include <math.h>

constexpr int Bc = 2, Sc = 2048, Dc = 1024, Hc = 16, HDc = 64;
constexpr int D3 = 3 * Dc;

typedef __bf16 bf16x8 __attribute__((ext_vector_type(8)));
typedef float f32x4 __attribute__((ext_vector_type(4)));

__device__ __forceinline__ void gll16(const void* g, void* l) {
  __builtin_amdgcn_global_load_lds((const __attribute__((address_space(1))) unsigned int*)g,
                                   (__attribute__((address_space(3))) unsigned int*)l,
                                   16, 0, 0);
}

__device__ __forceinline__ unsigned short f2bf(float v) {
  __hip_bfloat16 h = __float2bfloat16(v);
  return *(unsigned short*)&h;
}
__device__ __forceinline__ float b2f(unsigned short u) {
  unsigned v = ((unsigned)u) << 16;
  return __uint_as_float(v);
}

// ---------------- fp32 -> bf16 elementwise (4 elems/thread) ----------------
__global__ __launch_bounds__(256) void f2b_kernel(const float* __restrict__ in,
                                                  unsigned short* __restrict__ out) {
  int i = blockIdx.x * 256 + threadIdx.x;
  float4 v = ((const float4*)in)[i];
  ushort4 o;
  o.x = f2bf(v.x); o.y = f2bf(v.y); o.z = f2bf(v.z); o.w = f2bf(v.w);
  ((ushort4*)out)[i] = o;
}

// ---------------- RMSNorm: one block per row of 1024, bf16 out ----------------
__global__ __launch_bounds__(256) void rmsnorm_bf16_kernel(const float* __restrict__ in,
                                                           unsigned short* __restrict__ out) {
  int row = blockIdx.x;
  const float4* x4 = (const float4*)(in + (size_t)row * Dc);
  float4 v = x4[threadIdx.x];
  float s = v.x * v.x + v.y * v.y + v.z * v.z + v.w * v.w;
#pragma unroll
  for (int off = 1; off < 64; off <<= 1) s += __shfl_xor(s, off);
  __shared__ float wsum[4];
  if ((threadIdx.x & 63) == 0) wsum[threadIdx.x >> 6] = s;
  __syncthreads();
  float tot = wsum[0] + wsum[1] + wsum[2] + wsum[3];
  float r = rsqrtf(tot * (1.0f / Dc) + 1.1920928955078125e-07f);
  ushort4 o;
  o.x = f2bf(v.x * r); o.y = f2bf(v.y * r); o.z = f2bf(v.z * r); o.w = f2bf(v.w * r);
  ((ushort4*)(out + (size_t)row * Dc))[threadIdx.x] = o;
}

// ---------------- Householder product Q (64x64), 1 block, 64 threads ----------------
__global__ __launch_bounds__(64) void hh_kernel(const float* __restrict__ vs,
                                                float* __restrict__ Qout) {
  __shared__ float Qm[64][65];
  __shared__ float vsh[64];
  int t = threadIdx.x;
  for (int i = 0; i < 64; ++i) Qm[i][t] = (i == t) ? 1.0f : 0.0f;
  for (int it = 0; it < 32; ++it) {
    __syncthreads();
    vsh[t] = vs[it * 64 + t];
    __syncthreads();
    float nv = 0.0f;
    for (int i = 0; i < 64; ++i) nv += vsh[i] * vsh[i];
    float c = 2.0f / (nv + 1e-8f);
    float wj = 0.0f;
    for (int i = 0; i < 64; ++i) wj += vsh[i] * Qm[i][t];
    for (int i = 0; i < 64; ++i) Qm[i][t] -= c * vsh[i] * wj;
  }
  __syncthreads();
  for (int i = 0; i < 64; ++i) Qout[i * 64 + t] = Qm[i][t];
}

// ---------------- weight fold: out[n][:] = (Q @ W_head)[r][:] ----------------
// q rows scaled by 0.125*log2(e) (folds attention scale + exp2-domain softmax).
__global__ __launch_bounds__(256) void wqk_kernel(const float* __restrict__ W,
                                                  const float* __restrict__ Qm,
                                                  unsigned short* __restrict__ out) {
  int n = blockIdx.x;  // 0..2047
  int r = n & 63;
  int base = n & ~63;
  int t = threadIdx.x;
  float a0 = 0, a1 = 0, a2 = 0, a3 = 0;
  const float4* Wp = (const float4*)(W + (size_t)base * 1024) + t;
#pragma unroll 8
  for (int e = 0; e < 64; ++e) {
    float q = Qm[r * 64 + e];
    float4 wv = Wp[(size_t)e * 256];
    a0 += q * wv.x; a1 += q * wv.y; a2 += q * wv.z; a3 += q * wv.w;
  }
  float sc = (n < 1024) ? 0.18033688f : 1.0f;  // 0.125 * log2(e)
  ushort4 o;
  o.x = f2bf(a0 * sc); o.y = f2bf(a1 * sc); o.z = f2bf(a2 * sc); o.w = f2bf(a3 * sc);
  ((ushort4*)(out + (size_t)n * 1024))[t] = o;
}

// ---------------- rope cos/sin table ----------------
__global__ __launch_bounds__(256) void rtab_kernel(const float* __restrict__ rope_pos,
                                                   const float* __restrict__ inv_freq,
                                                   float2* __restrict__ tab) {
  int id = blockIdx.x * 256 + threadIdx.x;  // 65536 = 2048*32
  int s = id >> 5, d = id & 31;
  float pos = rope_pos[s * 2 + (d >> 4)];
  float emb = pos * inv_freq[d & 15];
  tab[id] = make_float2(cosf(emb), sinf(emb));
}

// ---------------- RoPE rotate + head-major relayout ----------------
__global__ __launch_bounds__(256) void rope_kernel(const unsigned short* __restrict__ qkv,
                                                   const float2* __restrict__ tab,
                                                   unsigned short* __restrict__ qb,
                                                   unsigned short* __restrict__ kb) {
  int t = threadIdx.x;
  int gid = blockIdx.x * 64 + (t >> 2);
  int sub = t & 3;
  int h = gid & 15;
  int which = (gid >> 4) & 1;
  int tok = gid >> 5;
  int s = tok & (Sc - 1), b = tok >> 11;
  const unsigned short* src = qkv + (size_t)tok * D3 + which * Dc + h * 64 + sub * 8;
  uint4 lov = *(const uint4*)src;
  uint4 hiv = *(const uint4*)(src + 32);
  const unsigned short* lp = (const unsigned short*)&lov;
  const unsigned short* hp = (const unsigned short*)&hiv;
  unsigned short olo[8], ohi[8];
  const float2* tp = tab + s * 32 + sub * 8;
#pragma unroll
  for (int i = 0; i < 8; ++i) {
    float2 cs = tp[i];
    float lo = b2f(lp[i]), hi = b2f(hp[i]);
    olo[i] = f2bf(lo * cs.x - hi * cs.y);
    ohi[i] = f2bf(hi * cs.x + lo * cs.y);
  }
  unsigned short* dst = (which ? kb : qb) + ((size_t)((b * Hc + h) * Sc + s)) * 64 + sub * 8;
  *(uint4*)dst = *(uint4*)olo;
  *(uint4*)(dst + 32) = *(uint4*)ohi;
}

// ---------------- V transpose-cast ----------------
__global__ __launch_bounds__(256) void vt_kernel(const unsigned short* __restrict__ qkv,
                                                 unsigned short* __restrict__ vtb) {
  __shared__ unsigned short tile[64 * 72];
  int st = blockIdx.x;
  int bh = blockIdx.y;
  int b = bh >> 4, h = bh & 15;
  int t = threadIdx.x;
  int srow = t >> 2, c16 = (t & 3) * 16;
  const unsigned short* src =
      qkv + (size_t)(b * Sc + st * 64 + srow) * D3 + 2 * Dc + h * 64 + c16;
  uint4 a0 = *(const uint4*)src;
  uint4 a1 = *(const uint4*)(src + 8);
  *(uint4*)(tile + srow * 72 + c16) = a0;
  *(uint4*)(tile + srow * 72 + c16 + 8) = a1;
  __syncthreads();
  int d = t >> 2, sch = (t & 3) * 16;
  unsigned short tmp[16];
#pragma unroll
  for (int i = 0; i < 16; ++i) tmp[i] = tile[(sch + i) * 72 + d];
  unsigned short* dst = vtb + ((size_t)(bh * 64 + d)) * Sc + st * 64 + sch;
  *(uint4*)dst = *(uint4*)tmp;
  *(uint4*)(dst + 8) = *(uint4*)(tmp + 8);
}

// ---------------- bf16 MFMA GEMM, 128x128 tile ----------------
// MODE 1: C bf16 = silu(A.W^T) * (A.W2^T)   MODE 3: C bf16
template <int MODE>
__global__ __launch_bounds__(256, 2) void mgemm(const unsigned short* __restrict__ A,
                                                const unsigned short* __restrict__ W,
                                                const unsigned short* __restrict__ W2,
                                                void* __restrict__ Cout,
                                                int M, int N, int K) {
  __shared__ unsigned short As[4096];
  __shared__ unsigned short Bs[4096];
  __shared__ unsigned short B2s[(MODE == 1) ? 4096 : 8];
  const int t = threadIdx.x;
  const int lane = t & 63;
  const int wave = t >> 6;
  const int wr = wave >> 1, wc = wave & 1;
  const int m0 = blockIdx.y * 128, n0 = blockIdx.x * 128;
  f32x4 acc[4][4] = {};
  f32x4 acc2[4][4] = {};
  const int srow = t >> 2;
  const int sch = (t & 3) * 8;
  const unsigned short* Ag = A + (size_t)(m0 + srow) * K + sch;
  const unsigned short* Wg = W + (size_t)(n0 + srow) * K + sch;
  const unsigned short* W2g = (MODE == 1) ? (W2 + (size_t)(n0 + srow) * K + sch) : nullptr;
  const size_t rstep = (size_t)64 * K;
  const int frow = lane & 15;
  const int fk = (lane >> 4) * 8;
  for (int k0 = 0; k0 < K; k0 += 32) {
    __syncthreads();
    gll16(Ag + k0, As + t * 8);
    gll16(Ag + k0 + rstep, As + 2048 + t * 8);
    gll16(Wg + k0, Bs + t * 8);
    gll16(Wg + k0 + rstep, Bs + 2048 + t * 8);
    if (MODE == 1) {
      gll16(W2g + k0, B2s + t * 8);
      gll16(W2g + k0 + rstep, B2s + 2048 + t * 8);
    }
    __syncthreads();
    bf16x8 af[4], bq[4];
#pragma unroll
    for (int i = 0; i < 4; ++i)
      af[i] = *(const bf16x8*)(As + (wr * 64 + i * 16 + frow) * 32 + fk);
#pragma unroll
    for (int j = 0; j < 4; ++j)
      bq[j] = *(const bf16x8*)(Bs + (wc * 64 + j * 16 + frow) * 32 + fk);
#pragma unroll
    for (int i = 0; i < 4; ++i)
#pragma unroll
      for (int j = 0; j < 4; ++j)
        acc[i][j] = __builtin_amdgcn_mfma_f32_16x16x32_bf16(af[i], bq[j], acc[i][j], 0, 0, 0);
    if (MODE == 1) {
#pragma unroll
      for (int j = 0; j < 4; ++j)
        bq[j] = *(const bf16x8*)(B2s + (wc * 64 + j * 16 + frow) * 32 + fk);
#pragma unroll
      for (int i = 0; i < 4; ++i)
#pragma unroll
        for (int j = 0; j < 4; ++j)
          acc2[i][j] = __builtin_amdgcn_mfma_f32_16x16x32_bf16(af[i], bq[j], acc2[i][j], 0, 0, 0);
    }
  }
  const int crow = wr * 64 + (lane >> 4) * 4;
  const int ccol = wc * 64 + (lane & 15);
#pragma unroll
  for (int i = 0; i < 4; ++i) {
#pragma unroll
    for (int j = 0; j < 4; ++j) {
#pragma unroll
      for (int r = 0; r < 4; ++r) {
        int row = m0 + crow + i * 16 + r;
        int col = n0 + ccol + j * 16;
        float v = acc[i][j][r];
        size_t off = (size_t)row * N + col;
        if (MODE == 1) {
          float sv = v / (1.0f + expf(-v));
          ((unsigned short*)Cout)[off] = f2bf(sv * acc2[i][j][r]);
        } else {
          ((unsigned short*)Cout)[off] = f2bf(v);
        }
      }
    }
  }
}

// ---------------- bf16 MFMA GEMM, 64x128 tile ----------------
// MODE 2: C fp32 = A.W^T + R
// MODE 4: Cout fp32 and Cout2 bf16
// MODE 5: Cout fp32 = R + R2 * sigmoid(A.W^T + bias[col])
template <int MODE>
__global__ __launch_bounds__(256, 3) void mgemm64(const unsigned short* __restrict__ A,
                                                  const unsigned short* __restrict__ W,
                                                  const float* __restrict__ R,
                                                  const float* __restrict__ R2,
                                                  const float* __restrict__ bias,
                                                  void* __restrict__ Cout,
                                                  void* __restrict__ Cout2,
                                                  int M, int N, int K) {
  __shared__ unsigned short As[2048];
  __shared__ unsigned short Bs[4096];
  const int t = threadIdx.x;
  const int lane = t & 63;
  const int wave = t >> 6;
  const int wr = wave >> 1, wc = wave & 1;
  const int m0 = blockIdx.y * 64, n0 = blockIdx.x * 128;
  f32x4 acc[2][4] = {};
  const int srow = t >> 2;
  const int sch = (t & 3) * 8;
  const unsigned short* Ag = A + (size_t)(m0 + srow) * K + sch;
  const unsigned short* Wg = W + (size_t)(n0 + srow) * K + sch;
  const size_t rstep = (size_t)64 * K;
  const int frow = lane & 15;
  const int fk = (lane >> 4) * 8;
  for (int k0 = 0; k0 < K; k0 += 32) {
    __syncthreads();
    gll16(Ag + k0, As + t * 8);
    gll16(Wg + k0, Bs + t * 8);
    gll16(Wg + k0 + rstep, Bs + 2048 + t * 8);
    __syncthreads();
    bf16x8 af[2], bq[4];
#pragma unroll
    for (int i = 0; i < 2; ++i)
      af[i] = *(const bf16x8*)(As + (wr * 32 + i * 16 + frow) * 32 + fk);
#pragma unroll
    for (int j = 0; j < 4; ++j)
      bq[j] = *(const bf16x8*)(Bs + (wc * 64 + j * 16 + frow) * 32 + fk);
#pragma unroll
    for (int i = 0; i < 2; ++i)
#pragma unroll
      for (int j = 0; j < 4; ++j)
        acc[i][j] = __builtin_amdgcn_mfma_f32_16x16x32_bf16(af[i], bq[j], acc[i][j], 0, 0, 0);
  }
  const int crow = wr * 32 + (lane >> 4) * 4;
  const int ccol = wc * 64 + (lane & 15);
#pragma unroll
  for (int i = 0; i < 2; ++i) {
#pragma unroll
    for (int j = 0; j < 4; ++j) {
#pragma unroll
      for (int r = 0; r < 4; ++r) {
        int row = m0 + crow + i * 16 + r;
        int col = n0 + ccol + j * 16;
        float v = acc[i][j][r];
        size_t off = (size_t)row * N + col;
        if (MODE == 2) {
          ((float*)Cout)[off] = v + R[off];
        } else if (MODE == 4) {
          ((float*)Cout)[off] = v;
          ((unsigned short*)Cout2)[off] = f2bf(v);
        } else {  // MODE 5
          float g = v + bias[col];
          float sg = 1.0f / (1.0f + expf(-g));
          ((float*)Cout)[off] = R[off] + R2[off] * sg;
        }
      }
    }
  }
}

// ---------------- MFMA flash attention, 128-query tiles ----------------
// qb: [b][h][s][64] bf16, pre-scaled by 0.125*log2e (exp2-domain softmax, no max-sub).
// kb: [b][h][s][64] bf16. vtb: [b][h][d][s] bf16. out: [b][s][h*64+d] bf16.
// Block: one (b,h) x 128-query tile; 4 waves; wave owns rows w*16 (chunk 0) and 64+w*16 (chunk 1).
__global__ __launch_bounds__(256) void mattn(const unsigned short* __restrict__ qb,
                                             const unsigned short* __restrict__ kb,
                                             const unsigned short* __restrict__ vtb,
                                             unsigned short* __restrict__ out) {
  __shared__ unsigned short Qs[8192];   // 128 x 64
  __shared__ unsigned short Ks[4096];   // 64 x 64
  __shared__ unsigned short Vts[4096];  // 64 d x 64 s
  __shared__ unsigned short Ps[4 * 16 * 72];
  const int qt = gridDim.x - 1 - blockIdx.x;  // heavy tiles dispatch first
  const int bh = blockIdx.y;
  const int b = bh >> 4, h = bh & 15;
  const int t = threadIdx.x, lane = t & 63, w = t >> 6;
  const int l15 = lane & 15, l4 = lane >> 4;
  const unsigned short* qbase = qb + ((size_t)bh * Sc + qt * 128) * 64;
  const unsigned short* kbase = kb + (size_t)bh * Sc * 64;
  const unsigned short* vbase = vtb + (size_t)bh * 64 * Sc;
  // stage Q once: 128 rows, chunk-swizzled (slot c holds global chunk c ^ (row&7))
#pragma unroll
  for (int i = 0; i < 4; ++i) {
    int idx = t + i * 256;
    int r = idx >> 3;
    int cg = (idx & 7) ^ (r & 7);
    gll16(qbase + (size_t)r * 64 + cg * 8, Qs + idx * 8);
  }
  bf16x8 qf[2][2];
  f32x4 oacc[2][4] = {};
  float lrow[2][4] = {};
  unsigned short* pw = Ps + w * 16 * 72;
  const int ktmax = 2 * qt + 1;
  for (int kt = 0; kt <= ktmax; ++kt) {
    __syncthreads();
    {
      int r = t >> 3;
      int cg = (t & 7) ^ (r & 7);
      gll16(kbase + (size_t)(kt * 64 + r) * 64 + cg * 8, Ks + t * 8);
      gll16(kbase + (size_t)(kt * 64 + r + 32) * 64 + cg * 8, Ks + 2048 + t * 8);
      gll16(vbase + (size_t)r * Sc + kt * 64 + cg * 8, Vts + t * 8);
      gll16(vbase + (size_t)(r + 32) * Sc + kt * 64 + cg * 8, Vts + 2048 + t * 8);
    }
    __syncthreads();
    if (kt == 0) {
#pragma unroll
      for (int ch = 0; ch < 2; ++ch) {
        int qrow = ch * 64 + w * 16 + l15;
#pragma unroll
        for (int kc = 0; kc < 2; ++kc)
          qf[ch][kc] = *(const bf16x8*)(Qs + qrow * 64 + (((kc * 4 + l4) ^ (l15 & 7)) * 8));
      }
    }
    const bool actA = (kt <= 2 * qt);
    // QK^T for both chunks, sharing kf
    f32x4 sc[2][4] = {};
#pragma unroll
    for (int kc = 0; kc < 2; ++kc) {
      bf16x8 kf[4];
#pragma unroll
      for (int j = 0; j < 4; ++j)
        kf[j] = *(const bf16x8*)(Ks + (j * 16 + l15) * 64 + (((kc * 4 + l4) ^ (l15 & 7)) * 8));
      if (actA) {
#pragma unroll
        for (int j = 0; j < 4; ++j)
          sc[0][j] = __builtin_amdgcn_mfma_f32_16x16x32_bf16(qf[0][kc], kf[j], sc[0][j], 0, 0, 0);
      }
#pragma unroll
      for (int j = 0; j < 4; ++j)
        sc[1][j] = __builtin_amdgcn_mfma_f32_16x16x32_bf16(qf[1][kc], kf[j], sc[1][j], 0, 0, 0);
    }
    // causal mask on the diagonal tiles (local row/col comparison)
    const int rl = w * 16 + l4 * 4;
    if (kt == 2 * qt) {
#pragma unroll
      for (int j = 0; j < 4; ++j)
#pragma unroll
        for (int r = 0; r < 4; ++r)
          if (j * 16 + l15 > rl + r) sc[0][j][r] = -INFINITY;
    }
    if (kt == ktmax) {
#pragma unroll
      for (int j = 0; j < 4; ++j)
#pragma unroll
        for (int r = 0; r < 4; ++r)
          if (j * 16 + l15 > rl + r) sc[1][j][r] = -INFINITY;
    }
    // V fragments once, shared by both chunks
    bf16x8 vf[2][4];
#pragma unroll
    for (int kc = 0; kc < 2; ++kc)
#pragma unroll
      for (int j = 0; j < 4; ++j)
        vf[kc][j] = *(const bf16x8*)(Vts + (j * 16 + l15) * 64 + (((kc * 4 + l4) ^ (l15 & 7)) * 8));
    // chunk A then chunk B: exp2 -> P to LDS -> PV (no max-sub, no rescale)
#pragma unroll
    for (int ch = 0; ch < 2; ++ch) {
      if (ch == 0 && !actA) continue;
#pragma unroll
      for (int j = 0; j < 4; ++j)
#pragma unroll
        for (int r = 0; r < 4; ++r) {
          float p = exp2f(sc[ch][j][r]);
          lrow[ch][r] += p;
          pw[(l4 * 4 + r) * 72 + j * 16 + l15] = f2bf(p);
        }
      __asm__ __volatile__("s_waitcnt lgkmcnt(0)" ::: "memory");
#pragma unroll
      for (int kc = 0; kc < 2; ++kc) {
        bf16x8 pf = *(const bf16x8*)(pw + l15 * 72 + kc * 32 + l4 * 8);
#pragma unroll
        for (int j = 0; j < 4; ++j)
          oacc[ch][j] = __builtin_amdgcn_mfma_f32_16x16x32_bf16(pf, vf[kc][j], oacc[ch][j], 0, 0, 0);
      }
    }
  }
  // deferred l reduction (over the 16 lanes sharing l4) and output
#pragma unroll
  for (int ch = 0; ch < 2; ++ch) {
#pragma unroll
    for (int r = 0; r < 4; ++r) {
      float s = lrow[ch][r];
      s += __shfl_xor(s, 1);
      s += __shfl_xor(s, 2);
      s += __shfl_xor(s, 4);
      s += __shfl_xor(s, 8);
      float inv = 1.0f / s;
#pragma unroll
      for (int j = 0; j < 4; ++j) {
        int srow = qt * 128 + ch * 64 + w * 16 + l4 * 4 + r;
        out[((size_t)(b * Sc + srow)) * Dc + h * 64 + j * 16 + l15] =
            f2bf(oacc[ch][j][r] * inv);
      }
    }
  }
}

extern "C" void kernel_launch(void* const* d_in, const int* in_sizes, int n_in,
                              void* d_out, int out_size, void* d_ws, size_t ws_size,
                              hipStream_t stream) {
  const float* x        = (const float*)d_in[0];
  const float* qkv_w    = (const float*)d_in[2];
  const float* out_w    = (const float*)d_in[3];
  const float* gate_w   = (const float*)d_in[4];
  const float* gate_b   = (const float*)d_in[5];
  const float* w12      = (const float*)d_in[6];
  const float* w3       = (const float*)d_in[7];
  const float* hh_vs    = (const float*)d_in[8];
  const float* inv_freq = (const float*)d_in[9];
  const float* rope_pos = (const float*)d_in[10];
  char* ws = (char*)d_ws;
  // lifetime-based slots (bytes), peak ~109.07 MB:
  unsigned short* woutb  = (unsigned short*)(ws + 0);          // 2 MiB  [-> outproj]
  float2*         rtab   = (float2*)(ws + 2097152);            // 512 KB [rtab -> rope]
  unsigned short* wqkvb  = (unsigned short*)(ws + 4194304);    // 6 MiB  [-> qkv GEMM]
  unsigned short* attnb  = (unsigned short*)(ws + 4194304);    // 8 MiB  [mattn -> outproj]
  float*          xmid   = (float*)(ws + 0);                   // 16 MiB [gate GEMM -> end]
  unsigned short* slotB  = (unsigned short*)(ws + 16777216);   // 8 MiB  xn | xn2
  float*          oproj  = (float*)(ws + 25165824);            // 16 MiB [outproj -> gate GEMM]
  unsigned short* w12b   = (unsigned short*)(ws + 25165824);   // 16 MiB [-> w12 GEMM]
  unsigned short* wgateb = (unsigned short*)(ws + 41943040);   // 2 MiB  [-> gate GEMM]
  unsigned short* w3b    = (unsigned short*)(ws + 41943040);   // 8 MiB  [-> w3 GEMM]
  unsigned short* qkvb   = (unsigned short*)(ws + 58720256);   // 24 MiB [qkv GEMM -> rope/vt]
  unsigned short* hbufb  = (unsigned short*)(ws + 58720256);   // 32 MiB [w12 -> w3 GEMM]
  unsigned short* qb     = (unsigned short*)(ws + 83886080);   // 8 MiB  [rope -> mattn]
  unsigned short* oprojb = (unsigned short*)(ws + 83886080);   // 8 MiB  [outproj -> gate GEMM]
  unsigned short* kb     = (unsigned short*)(ws + 92274688);   // 8 MiB
  unsigned short* vtb    = (unsigned short*)(ws + 100663296);  // 8 MiB
  float*          Qb     = (float*)(ws + 109051904);           // 16 KB
  float* outp = (float*)d_out;

  hh_kernel<<<1, 64, 0, stream>>>(hh_vs, Qb);
  rtab_kernel<<<256, 256, 0, stream>>>(rope_pos, inv_freq, rtab);
  wqk_kernel<<<2048, 256, 0, stream>>>(qkv_w, Qb, wqkvb);            // folded q,k weights
  f2b_kernel<<<1024, 256, 0, stream>>>(qkv_w + 2048 * 1024,
                                       wqkvb + 2048 * 1024);          // v weights plain cast
  f2b_kernel<<<1024, 256, 0, stream>>>(out_w, woutb);
  f2b_kernel<<<1024, 256, 0, stream>>>(gate_w, wgateb);
  rmsnorm_bf16_kernel<<<4096, 256, 0, stream>>>(x, slotB);
  mgemm<3><<<dim3(24, 32), 256, 0, stream>>>(slotB, wqkvb, nullptr, qkvb, 4096, 3072, 1024);
  rope_kernel<<<2048, 256, 0, stream>>>(qkvb, rtab, qb, kb);
  vt_kernel<<<dim3(32, 32), 256, 0, stream>>>(qkvb, vtb);
  mattn<<<dim3(16, 32), 256, 0, stream>>>(qb, kb, vtb, attnb);
  mgemm64<4><<<dim3(8, 64), 256, 0, stream>>>(attnb, woutb, nullptr, nullptr, nullptr,
                                              oproj, oprojb, 4096, 1024, 1024);
  mgemm64<5><<<dim3(8, 64), 256, 0, stream>>>(oprojb, wgateb, x, oproj, gate_b,
                                              xmid, nullptr, 4096, 1024, 1024);
  f2b_kernel<<<8192, 256, 0, stream>>>(w12, w12b);
  f2b_kernel<<<4096, 256, 0, stream>>>(w3, w3b);
  rmsnorm_bf16_kernel<<<4096, 256, 0, stream>>>(xmid, slotB);
  mgemm<1><<<dim3(32, 32), 256, 0, stream>>>(slotB, w12b, w12b + 4194304, hbufb,
                                             4096, 4096, 1024);
  mgemm64<2><<<dim3(8, 64), 256, 0, stream>>>(hbufb, w3b, xmid, nullptr, nullptr,
                                              outp, nullptr, 4096, 1024, 4096);
}